// Round 10
// baseline (603.802 us; speedup 1.0000x reference)
//
#include <hip/hip_runtime.h>
#include <math.h>
#include <stdint.h>

constexpr int kD  = 1024;   // model dim
constexpr int kB  = 512;    // batch
constexpr int kN  = 512;    // states per batch
constexpr int kDH = 512;    // head dim (H=2)

using bf16x8 = __attribute__((ext_vector_type(8))) short;
using f32x4v = __attribute__((ext_vector_type(4))) float;
using us8    = __attribute__((ext_vector_type(8))) unsigned short;
using us4    = __attribute__((ext_vector_type(4))) unsigned short;

__device__ __forceinline__ unsigned short f2bf(float f) {
    uint32_t u = __float_as_uint(f);
    u += 0x7fffu + ((u >> 16) & 1u);     // round-to-nearest-even
    return (unsigned short)(u >> 16);
}

__device__ __forceinline__ float bf2f(unsigned short s) {
    return __uint_as_float((uint32_t)s << 16);
}

__device__ __forceinline__ void async16(const void* g, void* l) {
    __builtin_amdgcn_global_load_lds(
        (const __attribute__((address_space(1))) uint32_t*)g,
        (__attribute__((address_space(3))) uint32_t*)l, 16, 0, 0);
}

// ---------------------------------------------------------------------------
// f32 -> bf16 convert with optional column restride/offset. (proven)
// ---------------------------------------------------------------------------
__global__ __launch_bounds__(256)
void cvt_bf16(const float* __restrict__ src, unsigned short* __restrict__ dst,
              int scols8, int dcols, int coloff, int n8)
{
    int idx = blockIdx.x * 256 + threadIdx.x;
    if (idx >= n8) return;
    int row = idx / scols8;
    int c = (idx - row * scols8) * 8;
    const float4* s = (const float4*)(src + (long)row * ((long)scols8 * 8) + c);
    float4 v0 = s[0], v1 = s[1];
    us8 o;
    o[0] = f2bf(v0.x); o[1] = f2bf(v0.y); o[2] = f2bf(v0.z); o[3] = f2bf(v0.w);
    o[4] = f2bf(v1.x); o[5] = f2bf(v1.y); o[6] = f2bf(v1.z); o[7] = f2bf(v1.w);
    *(us8*)(dst + (long)row * dcols + coloff + c) = o;
}

// ---------------------------------------------------------------------------
// wk transpose+convert with SCALE FOLDED IN (proven).
// ---------------------------------------------------------------------------
__global__ __launch_bounds__(256)
void tcvt_wk(const float* __restrict__ wk, unsigned short* __restrict__ dst)
{
    __shared__ float t[32][33];
    const int nt = blockIdx.x;     // 0..31 (n tiles)
    const int kt = blockIdx.y;     // 0..15 (k tiles)
    const int hh = blockIdx.z;     // head
    const int tx = threadIdx.x & 31, ty = threadIdx.x >> 5;   // 32 x 8
    const float scale = 0.044194173824159216f;   // 1/sqrt(512)
#pragma unroll
    for (int j = 0; j < 4; ++j)
        t[ty + j * 8][tx] = wk[(long)(hh * 512 + kt * 32 + ty + j * 8) * kD + nt * 32 + tx];
    __syncthreads();
#pragma unroll
    for (int j = 0; j < 4; ++j) {
        int n = nt * 32 + ty + j * 8;
        int k = kt * 32 + tx;
        dst[(long)hh * 524288 + (long)n * 512 + k] = f2bf(t[tx][ty + j * 8] * scale);
    }
}

// ---------------------------------------------------------------------------
// gemm64: bf16 MFMA GEMM, NT, 64x64 tile, BK=32, 256 threads (proven R8).
// ---------------------------------------------------------------------------
__global__ __launch_bounds__(256)
void gemm64(const unsigned short* __restrict__ A, int lda, long sAz,
            const unsigned short* __restrict__ B, int ldb, long sBz,
            float* __restrict__ Cf, int ldcf, long sCfz,
            unsigned short* __restrict__ Cb, int ldcb, long sCbz,
            const float* __restrict__ bias, long sbz, int K)
{
    __shared__ short As[4][64][8];
    __shared__ short Bs[4][64][8];
    A += (long)blockIdx.z * sAz;
    B += (long)blockIdx.z * sBz;

    const int tid = threadIdx.x;
    const int l = tid & 63, w = tid >> 6;
    const int wr = w >> 1, wc = w & 1;
    const int bm = blockIdx.y * 64, bn = blockIdx.x * 64;

    f32x4v acc[2][2] = {};

    for (int k0 = 0; k0 < K; k0 += 32) {
        __syncthreads();
        {
            int ks = tid >> 6, r = tid & 63;
            async16(A + (long)(bm + r) * lda + k0 + ks * 8, (short*)As + (long)tid * 8);
            async16(B + (long)(bn + r) * ldb + k0 + ks * 8, (short*)Bs + (long)tid * 8);
        }
        __syncthreads();   // vmcnt drained before barrier (m97 pattern)

        const int ks = l >> 4, rr = l & 15;
        bf16x8 a[2], b[2];
#pragma unroll
        for (int t = 0; t < 2; ++t) {
            a[t] = *(const bf16x8*)&As[ks][wr * 32 + t * 16 + rr][0];
            b[t] = *(const bf16x8*)&Bs[ks][wc * 32 + t * 16 + rr][0];
        }
#pragma unroll
        for (int mt = 0; mt < 2; ++mt)
#pragma unroll
            for (int nt = 0; nt < 2; ++nt)
                acc[mt][nt] = __builtin_amdgcn_mfma_f32_16x16x32_bf16(
                    a[mt], b[nt], acc[mt][nt], 0, 0, 0);
    }

    const int rr = l & 15, rg = l >> 4;
#pragma unroll
    for (int mt = 0; mt < 2; ++mt) {
#pragma unroll
        for (int nt = 0; nt < 2; ++nt) {
            const int n = bn + wc * 32 + nt * 16 + rr;
            float bb = bias ? bias[(long)blockIdx.z * sbz + n] : 0.f;
#pragma unroll
            for (int r = 0; r < 4; ++r) {
                const int m = bm + wr * 32 + mt * 16 + rg * 4 + r;
                float val = acc[mt][nt][r] + bb;
                if (Cf) Cf[(long)blockIdx.z * sCfz + (long)m * ldcf + n] = val;
                if (Cb) Cb[(long)blockIdx.z * sCbz + (long)m * ldcb + n] = f2bf(val);
            }
        }
    }
}

// ---------------------------------------------------------------------------
// gemm_gates: 64x128 tile, BK=64, dual-bias epilogue (proven R8).
// ---------------------------------------------------------------------------
__global__ __launch_bounds__(256)
void gemm_gates(const unsigned short* __restrict__ A, int lda,
                const unsigned short* __restrict__ B, int ldb,
                float* __restrict__ Cf, int ldcf,
                const float* __restrict__ b1, const float* __restrict__ b2,
                int K)
{
    __shared__ short As[8][64][8];
    __shared__ short Bs[8][128][8];

    const int tid = threadIdx.x;
    const int l = tid & 63, w = tid >> 6;
    const int wr = w >> 1, wc = w & 1;
    const int bm = blockIdx.y * 64, bn = blockIdx.x * 128;

    f32x4v acc[2][4] = {};

    for (int k0 = 0; k0 < K; k0 += 64) {
        __syncthreads();
#pragma unroll
        for (int j = 0; j < 2; ++j) {
            int ca = j * 256 + tid;            // 0..511: ks 0..7, row 0..63
            int ks = ca >> 6, r = ca & 63;
            async16(A + (long)(bm + r) * lda + k0 + ks * 8, (short*)As + (long)ca * 8);
        }
#pragma unroll
        for (int j = 0; j < 4; ++j) {
            int ca = j * 256 + tid;            // 0..1023: ks 0..7, row 0..127
            int ks = ca >> 7, r = ca & 127;
            async16(B + (long)(bn + r) * ldb + k0 + ks * 8, (short*)Bs + (long)ca * 8);
        }
        __syncthreads();

        const int ksl = l >> 4, rr = l & 15;
#pragma unroll
        for (int p = 0; p < 2; ++p) {
            bf16x8 a[2], b[4];
#pragma unroll
            for (int t = 0; t < 2; ++t)
                a[t] = *(const bf16x8*)&As[p * 4 + ksl][wr * 32 + t * 16 + rr][0];
#pragma unroll
            for (int t = 0; t < 4; ++t)
                b[t] = *(const bf16x8*)&Bs[p * 4 + ksl][wc * 64 + t * 16 + rr][0];
#pragma unroll
            for (int mt = 0; mt < 2; ++mt)
#pragma unroll
                for (int nt = 0; nt < 4; ++nt)
                    acc[mt][nt] = __builtin_amdgcn_mfma_f32_16x16x32_bf16(
                        a[mt], b[nt], acc[mt][nt], 0, 0, 0);
        }
    }

    const int rr = l & 15, rg = l >> 4;
#pragma unroll
    for (int mt = 0; mt < 2; ++mt) {
#pragma unroll
        for (int nt = 0; nt < 4; ++nt) {
            const int n = bn + wc * 64 + nt * 16 + rr;
            const float bb = b1[n] + b2[n];
#pragma unroll
            for (int r = 0; r < 4; ++r) {
                const int m = bm + wr * 32 + mt * 16 + rg * 4 + r;
                Cf[(long)m * ldcf + n] = acc[mt][nt][r] + bb;
            }
        }
    }
}

// ---------------------------------------------------------------------------
// attn7 (proven R7/R8): barrier-free streaming attention.
// ---------------------------------------------------------------------------
__global__ __launch_bounds__(512, 4)
void attn7(const float* __restrict__ xall,        // [B][N][D] f32
           const float* __restrict__ qt,          // [B][2][D] f32 (pre-scaled)
           unsigned short* __restrict__ spart_bf, // [B][8][2][1024] bf16
           float* __restrict__ mlpart)            // [B][8][2][2] f32
{
    const int b = blockIdx.x;
    const int tid = threadIdx.x;
    const int w = tid >> 6, l = tid & 63;

    float qa[16], qb[16];
    {
        const float* qp = qt + (long)b * 2048 + l * 4;
#pragma unroll
        for (int q = 0; q < 4; ++q) {
            float4 v0 = *(const float4*)(qp + q * 256);
            float4 v1 = *(const float4*)(qp + 1024 + q * 256);
            qa[q*4+0] = v0.x; qa[q*4+1] = v0.y; qa[q*4+2] = v0.z; qa[q*4+3] = v0.w;
            qb[q*4+0] = v1.x; qb[q*4+1] = v1.y; qb[q*4+2] = v1.z; qb[q*4+3] = v1.w;
        }
    }

    float m0 = -1e30f, l0 = 0.f, m1 = -1e30f, l1 = 0.f;
    float sa[16] = {}, sb[16] = {};

    const float* xr = xall + ((long)b * kN + w * 64) * kD + l * 4;

    for (int r = 0; r < 64; ++r) {
        float xv[16];
#pragma unroll
        for (int q = 0; q < 4; ++q) {
            float4 v = *(const float4*)(xr + q * 256);
            xv[q*4+0] = v.x; xv[q*4+1] = v.y; xv[q*4+2] = v.z; xv[q*4+3] = v.w;
        }
        xr += kD;

        float c0=0.f,c1=0.f,c2=0.f,c3=0.f, e0=0.f,e1=0.f,e2=0.f,e3=0.f;
#pragma unroll
        for (int q = 0; q < 4; ++q) {
            c0 += xv[q*4+0]*qa[q*4+0]; c1 += xv[q*4+1]*qa[q*4+1];
            c2 += xv[q*4+2]*qa[q*4+2]; c3 += xv[q*4+3]*qa[q*4+3];
            e0 += xv[q*4+0]*qb[q*4+0]; e1 += xv[q*4+1]*qb[q*4+1];
            e2 += xv[q*4+2]*qb[q*4+2]; e3 += xv[q*4+3]*qb[q*4+3];
        }
        float d0 = (c0 + c1) + (c2 + c3);
        float d1 = (e0 + e1) + (e2 + e3);
#pragma unroll
        for (int mm = 32; mm >= 1; mm >>= 1) {
            d0 += __shfl_xor(d0, mm);
            d1 += __shfl_xor(d1, mm);
        }

        if (d0 > m0 + 8.f) {                       // defer-max (T13), uniform
            float rsc = __expf(m0 - d0);
            l0 *= rsc;
#pragma unroll
            for (int j = 0; j < 16; ++j) sa[j] *= rsc;
            m0 = d0;
        }
        float p0 = __expf(d0 - m0);
        l0 += p0;

        if (d1 > m1 + 8.f) {
            float rsc = __expf(m1 - d1);
            l1 *= rsc;
#pragma unroll
            for (int j = 0; j < 16; ++j) sb[j] *= rsc;
            m1 = d1;
        }
        float p1 = __expf(d1 - m1);
        l1 += p1;

#pragma unroll
        for (int j = 0; j < 16; ++j) {
            sa[j] += p0 * xv[j];
            sb[j] += p1 * xv[j];
        }
    }

    unsigned short* sp0 = spart_bf + (((long)b * 8 + w) * 2 + 0) * 1024 + l * 4;
    unsigned short* sp1 = spart_bf + (((long)b * 8 + w) * 2 + 1) * 1024 + l * 4;
#pragma unroll
    for (int q = 0; q < 4; ++q) {
        us4 o0, o1;
        o0[0] = f2bf(sa[q*4+0]); o0[1] = f2bf(sa[q*4+1]);
        o0[2] = f2bf(sa[q*4+2]); o0[3] = f2bf(sa[q*4+3]);
        o1[0] = f2bf(sb[q*4+0]); o1[1] = f2bf(sb[q*4+1]);
        o1[2] = f2bf(sb[q*4+2]); o1[3] = f2bf(sb[q*4+3]);
        *(us4*)(sp0 + q * 256) = o0;
        *(us4*)(sp1 + q * 256) = o1;
    }

    if (l == 0) {
        float* mlp = mlpart + (((long)b * 8 + w) * 2) * 2;
        mlp[0] = m0; mlp[1] = l0; mlp[2] = m1; mlp[3] = l1;
    }
}

// ---------------------------------------------------------------------------
// Combine 8 per-wave partials -> normalized sums (proven).
// ---------------------------------------------------------------------------
__global__ __launch_bounds__(256)
void attn_combine8(const unsigned short* __restrict__ spart_bf,
                   const float* __restrict__ mlpart,
                   unsigned short* __restrict__ sac_bf)
{
    const int b = blockIdx.x;
    const int tid = threadIdx.x;
    const int h = tid >> 7, d0 = (tid & 127) * 8;

    float m[8], lv[8];
#pragma unroll
    for (int c = 0; c < 8; ++c) {
        const float* mlp = mlpart + (((long)b * 8 + c) * 2 + h) * 2;
        m[c] = mlp[0]; lv[c] = mlp[1];
    }
    float ms = m[0];
#pragma unroll
    for (int c = 1; c < 8; ++c) ms = fmaxf(ms, m[c]);
    float wgt[8], L = 0.f;
#pragma unroll
    for (int c = 0; c < 8; ++c) { wgt[c] = __expf(m[c] - ms); L += wgt[c] * lv[c]; }
    const float inv = 1.0f / L;

    float acc[8] = {};
#pragma unroll
    for (int c = 0; c < 8; ++c) {
        us8 sv = *(const us8*)(spart_bf + (((long)b * 8 + c) * 2 + h) * 1024 + d0);
#pragma unroll
        for (int j = 0; j < 8; ++j)
            acc[j] += wgt[c] * bf2f(sv[j]);
    }
    us8 o;
#pragma unroll
    for (int j = 0; j < 8; ++j) o[j] = f2bf(acc[j] * inv);
    *(us8*)(sac_bf + (long)b * 2048 + h * kD + d0) = o;
}

// ---------------------------------------------------------------------------
// Fused LSTM cell + LayerNorm (proven).
// ---------------------------------------------------------------------------
__device__ __forceinline__ float sigm(float x) { return 1.0f / (1.0f + __expf(-x)); }

__global__ __launch_bounds__(256)
void lstm_ln(const float* __restrict__ gates, const float* __restrict__ cin,
             const float* __restrict__ ln_w, const float* __restrict__ ln_b,
             float* __restrict__ out0, float* __restrict__ out1)
{
    __shared__ float red[2][4];
    __shared__ float stats[2];

    const int b = blockIdx.x;
    const int tid = threadIdx.x;
    const int d4 = tid * 4;
    const float* g = gates + (long)b * 4096;

    float4 gi = *(const float4*)(g + d4);
    float4 gf = *(const float4*)(g + 1024 + d4);
    float4 gg = *(const float4*)(g + 2048 + d4);
    float4 go = *(const float4*)(g + 3072 + d4);
    float4 cv = *(const float4*)(cin + (long)b * kD + d4);

    float iv[4] = {gi.x, gi.y, gi.z, gi.w};
    float fv[4] = {gf.x, gf.y, gf.z, gf.w};
    float gv[4] = {gg.x, gg.y, gg.z, gg.w};
    float ov[4] = {go.x, go.y, go.z, go.w};
    float cc[4] = {cv.x, cv.y, cv.z, cv.w};

    float nc[4], nh[4];
#pragma unroll
    for (int u = 0; u < 4; ++u) {
        nc[u] = sigm(fv[u]) * cc[u] + sigm(iv[u]) * tanhf(gv[u]);
        nh[u] = sigm(ov[u]) * tanhf(nc[u]);
    }
    *(float4*)(out1 + (long)b * kD + d4) = make_float4(nc[0], nc[1], nc[2], nc[3]);

    float sum = nh[0] + nh[1] + nh[2] + nh[3];
    float ss  = nh[0]*nh[0] + nh[1]*nh[1] + nh[2]*nh[2] + nh[3]*nh[3];
#pragma unroll
    for (int m = 32; m >= 1; m >>= 1) {
        sum += __shfl_xor(sum, m);
        ss  += __shfl_xor(ss, m);
    }
    const int wave = tid >> 6, lane = tid & 63;
    if (lane == 0) { red[0][wave] = sum; red[1][wave] = ss; }
    __syncthreads();
    if (tid == 0) {
        float s = red[0][0] + red[0][1] + red[0][2] + red[0][3];
        float q = red[1][0] + red[1][1] + red[1][2] + red[1][3];
        float mu = s / (float)kD;
        float var = q / (float)kD - mu * mu;
        stats[0] = mu;
        stats[1] = rsqrtf(var + 1e-5f);
    }
    __syncthreads();
    const float mu = stats[0], rstd = stats[1];
    float4 lw = *(const float4*)(ln_w + d4);
    float4 lb = *(const float4*)(ln_b + d4);
    float lwv[4] = {lw.x, lw.y, lw.z, lw.w};
    float lbv[4] = {lb.x, lb.y, lb.z, lb.w};
    float o[4];
#pragma unroll
    for (int u = 0; u < 4; ++u)
        o[u] = (nh[u] - mu) * rstd * lwv[u] + lbv[u];
    *(float4*)(out0 + (long)b * kD + d4) = make_float4(o[0], o[1], o[2], o[3]);
}

// ---------------------------------------------------------------------------
extern "C" void kernel_launch(void* const* d_in, const int* in_sizes, int n_in,
                              void* d_out, int out_size, void* d_ws, size_t ws_size,
                              hipStream_t stream)
{
    (void)in_sizes; (void)n_in; (void)out_size;

    const float* h    = (const float*)d_in[0];
    const float* c    = (const float*)d_in[1];
    const float* xall = (const float*)d_in[2];
    const float* ext  = (const float*)d_in[3];
    const float* in_w = (const float*)d_in[4];
    const float* in_b = (const float*)d_in[5];
    const float* wo   = (const float*)d_in[6];
    const float* bo   = (const float*)d_in[7];
    const float* w_ih = (const float*)d_in[8];
    const float* b_ih = (const float*)d_in[9];
    const float* w_hh = (const float*)d_in[10];
    const float* b_hh = (const float*)d_in[11];
    const float* ln_w = (const float*)d_in[12];
    const float* ln_b = (const float*)d_in[13];

    float* out0 = (float*)d_out;              // LN(new_h) [512x1024]
    float* out1 = out0 + (long)kB * kD;       // new_c     [512x1024]

    // ---- workspace layout (identical offsets to round 8)
    char* p = (char*)d_ws;
    const size_t need = 63062016ull;
    if (ws_size < need) return;

    p += 16384;                                                  // (spare)
    unsigned short* h_bf   = (unsigned short*)p; p += 1048576;   // [512][1024]
    unsigned short* wq_bf  = (unsigned short*)p; p += 2097152;   // [1024][1024]
    unsigned short* wkT_bf = (unsigned short*)p; p += 2097152;   // [2][1024][512]
    unsigned short* wv_bf  = (unsigned short*)p; p += 2097152;   // [1024][1024]
    unsigned short* wo_bf  = (unsigned short*)p; p += 2097152;   // [1024][1024]
    unsigned short* q_bf   = (unsigned short*)p; p += 1048576;   // [512][1024]
    unsigned short* sac_bf = (unsigned short*)p; p += 2097152;   // [512][2048]
    unsigned short* ctx_bf = (unsigned short*)p; p += 1048576;   // [512][1024]
    unsigned short* acat   = (unsigned short*)p; p += 3145728;   // [512][3072]
    unsigned short* wcat   = (unsigned short*)p; p += 25165824;  // [4096][3072]
    // overlay region: {qtl, spart, mlpart} (attention) / {gates} (after combine)
    char* ov = p;
    float*          qtl      = (float*)ov;                       // [512][2][1024] f32
    unsigned short* spart_bf = (unsigned short*)(ov + 4194304);  // [512][8][2][1024] bf16
    float*          mlpart   = (float*)(ov + 4194304 + 16777216);// [512][8][2][2]
    float*          gates    = (float*)ov;                       // [512][4096] (aliases, later)

    const float* wk_f = in_w + (long)kD * kD;
    const float* bq = in_b;
    const float* bv = in_b + 2 * kD;

    auto cvt = [&](const float* src, unsigned short* dst, int rows, int scols,
                   int dcols, int coloff) {
        int n8 = rows * (scols / 8);
        cvt_bf16<<<(n8 + 255) / 256, 256, 0, stream>>>(src, dst, scols / 8, dcols, coloff, n8);
    };

    // ---- conversions (proven forms)
    cvt(h, h_bf, 512, 1024, 1024, 0);
    cvt(in_w, wq_bf, 1024, 1024, 1024, 0);
    tcvt_wk<<<dim3(32, 16, 2), 256, 0, stream>>>(wk_f, wkT_bf);
    cvt(in_w + 2L * kD * kD, wv_bf, 1024, 1024, 1024, 0);
    cvt(wo, wo_bf, 1024, 1024, 1024, 0);
    cvt(w_ih, wcat, 4096, 2048, 3072, 0);
    cvt(w_hh, wcat, 4096, 1024, 3072, 2048);

    // 1. q_bf = bf16(h @ wq^T + bq)
    gemm64<<<dim3(16, 8, 1), 256, 0, stream>>>(
        h_bf, 1024, 0, wq_bf, 1024, 0,
        nullptr, 0, 0, q_bf, 1024, 0, bq, 0, 1024);

    // 2. qtl[:, z, :] = q_z @ wkT_z^T   (f32 out; scale pre-folded in wkT)
    gemm64<<<dim3(16, 8, 2), 256, 0, stream>>>(
        q_bf, 1024, 512, wkT_bf, 512, 524288,
        qtl, 2048, 1024, nullptr, 0, 0, nullptr, 0, 512);

    // 3. streaming attention -> partials.
    // MEASUREMENT ROUND: launched TWICE (idempotent — writes identical values;
    // deterministic). T_attn = dur_us(this round) - 409 (R8 anchor).
    attn7<<<kB, 512, 0, stream>>>(xall, qtl, spart_bf, mlpart);
    attn7<<<kB, 512, 0, stream>>>(xall, qtl, spart_bf, mlpart);

    // 4. combine 8 partials -> sac_bf (bf16)
    attn_combine8<<<kB, 256, 0, stream>>>(spart_bf, mlpart, sac_bf);

    // 5. ctx_bf[:, z*512:] = bf16(s_z @ wv_z^T + bv_z)
    gemm64<<<dim3(8, 8, 2), 256, 0, stream>>>(
        sac_bf, 2048, 1024, wv_bf, 1024, 524288,
        nullptr, 0, 0, ctx_bf, 1024, 512, bv, 512, 1024);

    // 6. acat[:, 0:1024] = bf16(ctx @ wo^T + bo)
    gemm64<<<dim3(16, 8, 1), 256, 0, stream>>>(
        ctx_bf, 1024, 0, wo_bf, 1024, 0,
        nullptr, 0, 0, acat, 3072, 0, bo, 0, 1024);

    // remaining acat columns
    cvt(ext, acat, 512, 1024, 3072, 1024);
    cvt(h,   acat, 512, 1024, 3072, 2048);

    // 7. gates = acat @ wcat^T + b_ih + b_hh   (BK=64, dual-bias)
    gemm_gates<<<dim3(32, 8), 256, 0, stream>>>(
        acat, 3072, wcat, 3072, gates, 4096, b_ih, b_hh, 3072);

    // 8. LSTM cell + LayerNorm
    lstm_ln<<<kB, 256, 0, stream>>>(gates, c, ln_w, ln_b, out0, out1);
}

// Round 12
// 396.517 us; speedup vs baseline: 1.5228x; 1.5228x over previous
//
#include <hip/hip_runtime.h>
#include <math.h>
#include <stdint.h>

constexpr int kD  = 1024;   // model dim
constexpr int kB  = 512;    // batch
constexpr int kN  = 512;    // states per batch
constexpr int kDH = 512;    // head dim (H=2)

using bf16x8 = __attribute__((ext_vector_type(8))) short;
using f32x4v = __attribute__((ext_vector_type(4))) float;
using us8    = __attribute__((ext_vector_type(8))) unsigned short;
using us4    = __attribute__((ext_vector_type(4))) unsigned short;

__device__ __forceinline__ unsigned short f2bf(float f) {
    uint32_t u = __float_as_uint(f);
    u += 0x7fffu + ((u >> 16) & 1u);     // round-to-nearest-even
    return (unsigned short)(u >> 16);
}

__device__ __forceinline__ float bf2f(unsigned short s) {
    return __uint_as_float((uint32_t)s << 16);
}

__device__ __forceinline__ void async16(const void* g, void* l) {
    __builtin_amdgcn_global_load_lds(
        (const __attribute__((address_space(1))) uint32_t*)g,
        (__attribute__((address_space(3))) uint32_t*)l, 16, 0, 0);
}

// ---------------------------------------------------------------------------
// f32 -> bf16 convert with optional column restride/offset. (proven; the
// mega-cvt variant is BANNED: 3/3 crashes R4/R5/R11, 7/7 passes without)
// ---------------------------------------------------------------------------
__global__ __launch_bounds__(256)
void cvt_bf16(const float* __restrict__ src, unsigned short* __restrict__ dst,
              int scols8, int dcols, int coloff, int n8)
{
    int idx = blockIdx.x * 256 + threadIdx.x;
    if (idx >= n8) return;
    int row = idx / scols8;
    int c = (idx - row * scols8) * 8;
    const float4* s = (const float4*)(src + (long)row * ((long)scols8 * 8) + c);
    float4 v0 = s[0], v1 = s[1];
    us8 o;
    o[0] = f2bf(v0.x); o[1] = f2bf(v0.y); o[2] = f2bf(v0.z); o[3] = f2bf(v0.w);
    o[4] = f2bf(v1.x); o[5] = f2bf(v1.y); o[6] = f2bf(v1.z); o[7] = f2bf(v1.w);
    *(us8*)(dst + (long)row * dcols + coloff + c) = o;
}

// ---------------------------------------------------------------------------
// wk transpose+convert with SCALE FOLDED IN (proven).
// ---------------------------------------------------------------------------
__global__ __launch_bounds__(256)
void tcvt_wk(const float* __restrict__ wk, unsigned short* __restrict__ dst)
{
    __shared__ float t[32][33];
    const int nt = blockIdx.x;     // 0..31 (n tiles)
    const int kt = blockIdx.y;     // 0..15 (k tiles)
    const int hh = blockIdx.z;     // head
    const int tx = threadIdx.x & 31, ty = threadIdx.x >> 5;   // 32 x 8
    const float scale = 0.044194173824159216f;   // 1/sqrt(512)
#pragma unroll
    for (int j = 0; j < 4; ++j)
        t[ty + j * 8][tx] = wk[(long)(hh * 512 + kt * 32 + ty + j * 8) * kD + nt * 32 + tx];
    __syncthreads();
#pragma unroll
    for (int j = 0; j < 4; ++j) {
        int n = nt * 32 + ty + j * 8;
        int k = kt * 32 + tx;
        dst[(long)hh * 524288 + (long)n * 512 + k] = f2bf(t[tx][ty + j * 8] * scale);
    }
}

// ---------------------------------------------------------------------------
// gemm64: bf16 MFMA GEMM, NT, 64x64 tile, BK=32, 256 threads (proven R8).
// ---------------------------------------------------------------------------
__global__ __launch_bounds__(256)
void gemm64(const unsigned short* __restrict__ A, int lda, long sAz,
            const unsigned short* __restrict__ B, int ldb, long sBz,
            float* __restrict__ Cf, int ldcf, long sCfz,
            unsigned short* __restrict__ Cb, int ldcb, long sCbz,
            const float* __restrict__ bias, long sbz, int K)
{
    __shared__ short As[4][64][8];
    __shared__ short Bs[4][64][8];
    A += (long)blockIdx.z * sAz;
    B += (long)blockIdx.z * sBz;

    const int tid = threadIdx.x;
    const int l = tid & 63, w = tid >> 6;
    const int wr = w >> 1, wc = w & 1;
    const int bm = blockIdx.y * 64, bn = blockIdx.x * 64;

    f32x4v acc[2][2] = {};

    for (int k0 = 0; k0 < K; k0 += 32) {
        __syncthreads();
        {
            int ks = tid >> 6, r = tid & 63;
            async16(A + (long)(bm + r) * lda + k0 + ks * 8, (short*)As + (long)tid * 8);
            async16(B + (long)(bn + r) * ldb + k0 + ks * 8, (short*)Bs + (long)tid * 8);
        }
        __syncthreads();   // vmcnt drained before barrier (m97 pattern)

        const int ks = l >> 4, rr = l & 15;
        bf16x8 a[2], b[2];
#pragma unroll
        for (int t = 0; t < 2; ++t) {
            a[t] = *(const bf16x8*)&As[ks][wr * 32 + t * 16 + rr][0];
            b[t] = *(const bf16x8*)&Bs[ks][wc * 32 + t * 16 + rr][0];
        }
#pragma unroll
        for (int mt = 0; mt < 2; ++mt)
#pragma unroll
            for (int nt = 0; nt < 2; ++nt)
                acc[mt][nt] = __builtin_amdgcn_mfma_f32_16x16x32_bf16(
                    a[mt], b[nt], acc[mt][nt], 0, 0, 0);
    }

    const int rr = l & 15, rg = l >> 4;
#pragma unroll
    for (int mt = 0; mt < 2; ++mt) {
#pragma unroll
        for (int nt = 0; nt < 2; ++nt) {
            const int n = bn + wc * 32 + nt * 16 + rr;
            float bb = bias ? bias[(long)blockIdx.z * sbz + n] : 0.f;
#pragma unroll
            for (int r = 0; r < 4; ++r) {
                const int m = bm + wr * 32 + mt * 16 + rg * 4 + r;
                float val = acc[mt][nt][r] + bb;
                if (Cf) Cf[(long)blockIdx.z * sCfz + (long)m * ldcf + n] = val;
                if (Cb) Cb[(long)blockIdx.z * sCbz + (long)m * ldcb + n] = f2bf(val);
            }
        }
    }
}

// ---------------------------------------------------------------------------
// gemm_gates64: 64x64 tile, BK=64, dual-bias epilogue.
// Grid 64x8 = 512 blocks -> 2 blocks/CU, 8 waves/CU (the R8 gates kernel ran
// 256 blocks = 1 block/CU at 4 waves: every barrier stalled the whole CU).
// ---------------------------------------------------------------------------
__global__ __launch_bounds__(256)
void gemm_gates64(const unsigned short* __restrict__ A, int lda,
                  const unsigned short* __restrict__ B, int ldb,
                  float* __restrict__ Cf, int ldcf,
                  const float* __restrict__ b1, const float* __restrict__ b2,
                  int K)
{
    __shared__ short As[8][64][8];
    __shared__ short Bs[8][64][8];

    const int tid = threadIdx.x;
    const int l = tid & 63, w = tid >> 6;
    const int wr = w >> 1, wc = w & 1;
    const int bm = blockIdx.y * 64, bn = blockIdx.x * 64;

    f32x4v acc[2][2] = {};

    for (int k0 = 0; k0 < K; k0 += 64) {
        __syncthreads();
#pragma unroll
        for (int j = 0; j < 2; ++j) {
            int ca = j * 256 + tid;            // 0..511: ks 0..7, row 0..63
            int ks = ca >> 6, r = ca & 63;
            async16(A + (long)(bm + r) * lda + k0 + ks * 8, (short*)As + (long)ca * 8);
            async16(B + (long)(bn + r) * ldb + k0 + ks * 8, (short*)Bs + (long)ca * 8);
        }
        __syncthreads();   // vmcnt drained before barrier (m97 pattern)

        const int ksl = l >> 4, rr = l & 15;
#pragma unroll
        for (int p = 0; p < 2; ++p) {
            bf16x8 a[2], b[2];
#pragma unroll
            for (int t = 0; t < 2; ++t) {
                a[t] = *(const bf16x8*)&As[p * 4 + ksl][wr * 32 + t * 16 + rr][0];
                b[t] = *(const bf16x8*)&Bs[p * 4 + ksl][wc * 32 + t * 16 + rr][0];
            }
#pragma unroll
            for (int mt = 0; mt < 2; ++mt)
#pragma unroll
                for (int nt = 0; nt < 2; ++nt)
                    acc[mt][nt] = __builtin_amdgcn_mfma_f32_16x16x32_bf16(
                        a[mt], b[nt], acc[mt][nt], 0, 0, 0);
        }
    }

    const int rr = l & 15, rg = l >> 4;
#pragma unroll
    for (int mt = 0; mt < 2; ++mt) {
#pragma unroll
        for (int nt = 0; nt < 2; ++nt) {
            const int n = bn + wc * 32 + nt * 16 + rr;
            const float bb = b1[n] + b2[n];
#pragma unroll
            for (int r = 0; r < 4; ++r) {
                const int m = bm + wr * 32 + mt * 16 + rg * 4 + r;
                Cf[(long)m * ldcf + n] = acc[mt][nt][r] + bb;
            }
        }
    }
}

// ---------------------------------------------------------------------------
// attn7 (proven R7/R8, at ~88% of achievable HBM BW [R10 measurement:
// T_attn = 195 us on a 1.10 GB stream] — frozen).
// ---------------------------------------------------------------------------
__global__ __launch_bounds__(512, 4)
void attn7(const float* __restrict__ xall,        // [B][N][D] f32
           const float* __restrict__ qt,          // [B][2][D] f32 (pre-scaled)
           unsigned short* __restrict__ spart_bf, // [B][8][2][1024] bf16
           float* __restrict__ mlpart)            // [B][8][2][2] f32
{
    const int b = blockIdx.x;
    const int tid = threadIdx.x;
    const int w = tid >> 6, l = tid & 63;

    float qa[16], qb[16];
    {
        const float* qp = qt + (long)b * 2048 + l * 4;
#pragma unroll
        for (int q = 0; q < 4; ++q) {
            float4 v0 = *(const float4*)(qp + q * 256);
            float4 v1 = *(const float4*)(qp + 1024 + q * 256);
            qa[q*4+0] = v0.x; qa[q*4+1] = v0.y; qa[q*4+2] = v0.z; qa[q*4+3] = v0.w;
            qb[q*4+0] = v1.x; qb[q*4+1] = v1.y; qb[q*4+2] = v1.z; qb[q*4+3] = v1.w;
        }
    }

    float m0 = -1e30f, l0 = 0.f, m1 = -1e30f, l1 = 0.f;
    float sa[16] = {}, sb[16] = {};

    const float* xr = xall + ((long)b * kN + w * 64) * kD + l * 4;

    for (int r = 0; r < 64; ++r) {
        float xv[16];
#pragma unroll
        for (int q = 0; q < 4; ++q) {
            float4 v = *(const float4*)(xr + q * 256);
            xv[q*4+0] = v.x; xv[q*4+1] = v.y; xv[q*4+2] = v.z; xv[q*4+3] = v.w;
        }
        xr += kD;

        float c0=0.f,c1=0.f,c2=0.f,c3=0.f, e0=0.f,e1=0.f,e2=0.f,e3=0.f;
#pragma unroll
        for (int q = 0; q < 4; ++q) {
            c0 += xv[q*4+0]*qa[q*4+0]; c1 += xv[q*4+1]*qa[q*4+1];
            c2 += xv[q*4+2]*qa[q*4+2]; c3 += xv[q*4+3]*qa[q*4+3];
            e0 += xv[q*4+0]*qb[q*4+0]; e1 += xv[q*4+1]*qb[q*4+1];
            e2 += xv[q*4+2]*qb[q*4+2]; e3 += xv[q*4+3]*qb[q*4+3];
        }
        float d0 = (c0 + c1) + (c2 + c3);
        float d1 = (e0 + e1) + (e2 + e3);
#pragma unroll
        for (int mm = 32; mm >= 1; mm >>= 1) {
            d0 += __shfl_xor(d0, mm);
            d1 += __shfl_xor(d1, mm);
        }

        if (d0 > m0 + 8.f) {                       // defer-max (T13), uniform
            float rsc = __expf(m0 - d0);
            l0 *= rsc;
#pragma unroll
            for (int j = 0; j < 16; ++j) sa[j] *= rsc;
            m0 = d0;
        }
        float p0 = __expf(d0 - m0);
        l0 += p0;

        if (d1 > m1 + 8.f) {
            float rsc = __expf(m1 - d1);
            l1 *= rsc;
#pragma unroll
            for (int j = 0; j < 16; ++j) sb[j] *= rsc;
            m1 = d1;
        }
        float p1 = __expf(d1 - m1);
        l1 += p1;

#pragma unroll
        for (int j = 0; j < 16; ++j) {
            sa[j] += p0 * xv[j];
            sb[j] += p1 * xv[j];
        }
    }

    unsigned short* sp0 = spart_bf + (((long)b * 8 + w) * 2 + 0) * 1024 + l * 4;
    unsigned short* sp1 = spart_bf + (((long)b * 8 + w) * 2 + 1) * 1024 + l * 4;
#pragma unroll
    for (int q = 0; q < 4; ++q) {
        us4 o0, o1;
        o0[0] = f2bf(sa[q*4+0]); o0[1] = f2bf(sa[q*4+1]);
        o0[2] = f2bf(sa[q*4+2]); o0[3] = f2bf(sa[q*4+3]);
        o1[0] = f2bf(sb[q*4+0]); o1[1] = f2bf(sb[q*4+1]);
        o1[2] = f2bf(sb[q*4+2]); o1[3] = f2bf(sb[q*4+3]);
        *(us4*)(sp0 + q * 256) = o0;
        *(us4*)(sp1 + q * 256) = o1;
    }

    if (l == 0) {
        float* mlp = mlpart + (((long)b * 8 + w) * 2) * 2;
        mlp[0] = m0; mlp[1] = l0; mlp[2] = m1; mlp[3] = l1;
    }
}

// ---------------------------------------------------------------------------
// Combine 8 per-wave partials -> normalized sums (proven).
// ---------------------------------------------------------------------------
__global__ __launch_bounds__(256)
void attn_combine8(const unsigned short* __restrict__ spart_bf,
                   const float* __restrict__ mlpart,
                   unsigned short* __restrict__ sac_bf)
{
    const int b = blockIdx.x;
    const int tid = threadIdx.x;
    const int h = tid >> 7, d0 = (tid & 127) * 8;

    float m[8], lv[8];
#pragma unroll
    for (int c = 0; c < 8; ++c) {
        const float* mlp = mlpart + (((long)b * 8 + c) * 2 + h) * 2;
        m[c] = mlp[0]; lv[c] = mlp[1];
    }
    float ms = m[0];
#pragma unroll
    for (int c = 1; c < 8; ++c) ms = fmaxf(ms, m[c]);
    float wgt[8], L = 0.f;
#pragma unroll
    for (int c = 0; c < 8; ++c) { wgt[c] = __expf(m[c] - ms); L += wgt[c] * lv[c]; }
    const float inv = 1.0f / L;

    float acc[8] = {};
#pragma unroll
    for (int c = 0; c < 8; ++c) {
        us8 sv = *(const us8*)(spart_bf + (((long)b * 8 + c) * 2 + h) * 1024 + d0);
#pragma unroll
        for (int j = 0; j < 8; ++j)
            acc[j] += wgt[c] * bf2f(sv[j]);
    }
    us8 o;
#pragma unroll
    for (int j = 0; j < 8; ++j) o[j] = f2bf(acc[j] * inv);
    *(us8*)(sac_bf + (long)b * 2048 + h * kD + d0) = o;
}

// ---------------------------------------------------------------------------
// Fused LSTM cell + LayerNorm (proven).
// ---------------------------------------------------------------------------
__device__ __forceinline__ float sigm(float x) { return 1.0f / (1.0f + __expf(-x)); }

__global__ __launch_bounds__(256)
void lstm_ln(const float* __restrict__ gates, const float* __restrict__ cin,
             const float* __restrict__ ln_w, const float* __restrict__ ln_b,
             float* __restrict__ out0, float* __restrict__ out1)
{
    __shared__ float red[2][4];
    __shared__ float stats[2];

    const int b = blockIdx.x;
    const int tid = threadIdx.x;
    const int d4 = tid * 4;
    const float* g = gates + (long)b * 4096;

    float4 gi = *(const float4*)(g + d4);
    float4 gf = *(const float4*)(g + 1024 + d4);
    float4 gg = *(const float4*)(g + 2048 + d4);
    float4 go = *(const float4*)(g + 3072 + d4);
    float4 cv = *(const float4*)(cin + (long)b * kD + d4);

    float iv[4] = {gi.x, gi.y, gi.z, gi.w};
    float fv[4] = {gf.x, gf.y, gf.z, gf.w};
    float gv[4] = {gg.x, gg.y, gg.z, gg.w};
    float ov[4] = {go.x, go.y, go.z, go.w};
    float cc[4] = {cv.x, cv.y, cv.z, cv.w};

    float nc[4], nh[4];
#pragma unroll
    for (int u = 0; u < 4; ++u) {
        nc[u] = sigm(fv[u]) * cc[u] + sigm(iv[u]) * tanhf(gv[u]);
        nh[u] = sigm(ov[u]) * tanhf(nc[u]);
    }
    *(float4*)(out1 + (long)b * kD + d4) = make_float4(nc[0], nc[1], nc[2], nc[3]);

    float sum = nh[0] + nh[1] + nh[2] + nh[3];
    float ss  = nh[0]*nh[0] + nh[1]*nh[1] + nh[2]*nh[2] + nh[3]*nh[3];
#pragma unroll
    for (int m = 32; m >= 1; m >>= 1) {
        sum += __shfl_xor(sum, m);
        ss  += __shfl_xor(ss, m);
    }
    const int wave = tid >> 6, lane = tid & 63;
    if (lane == 0) { red[0][wave] = sum; red[1][wave] = ss; }
    __syncthreads();
    if (tid == 0) {
        float s = red[0][0] + red[0][1] + red[0][2] + red[0][3];
        float q = red[1][0] + red[1][1] + red[1][2] + red[1][3];
        float mu = s / (float)kD;
        float var = q / (float)kD - mu * mu;
        stats[0] = mu;
        stats[1] = rsqrtf(var + 1e-5f);
    }
    __syncthreads();
    const float mu = stats[0], rstd = stats[1];
    float4 lw = *(const float4*)(ln_w + d4);
    float4 lb = *(const float4*)(ln_b + d4);
    float lwv[4] = {lw.x, lw.y, lw.z, lw.w};
    float lbv[4] = {lb.x, lb.y, lb.z, lb.w};
    float o[4];
#pragma unroll
    for (int u = 0; u < 4; ++u)
        o[u] = (nh[u] - mu) * rstd * lwv[u] + lbv[u];
    *(float4*)(out0 + (long)b * kD + d4) = make_float4(o[0], o[1], o[2], o[3]);
}

// ---------------------------------------------------------------------------
extern "C" void kernel_launch(void* const* d_in, const int* in_sizes, int n_in,
                              void* d_out, int out_size, void* d_ws, size_t ws_size,
                              hipStream_t stream)
{
    (void)in_sizes; (void)n_in; (void)out_size;

    const float* h    = (const float*)d_in[0];
    const float* c    = (const float*)d_in[1];
    const float* xall = (const float*)d_in[2];
    const float* ext  = (const float*)d_in[3];
    const float* in_w = (const float*)d_in[4];
    const float* in_b = (const float*)d_in[5];
    const float* wo   = (const float*)d_in[6];
    const float* bo   = (const float*)d_in[7];
    const float* w_ih = (const float*)d_in[8];
    const float* b_ih = (const float*)d_in[9];
    const float* w_hh = (const float*)d_in[10];
    const float* b_hh = (const float*)d_in[11];
    const float* ln_w = (const float*)d_in[12];
    const float* ln_b = (const float*)d_in[13];

    float* out0 = (float*)d_out;              // LN(new_h) [512x1024]
    float* out1 = out0 + (long)kB * kD;       // new_c     [512x1024]

    // ---- workspace layout (identical offsets to round 8)
    char* p = (char*)d_ws;
    const size_t need = 63062016ull;
    if (ws_size < need) return;

    p += 16384;                                                  // (spare)
    unsigned short* h_bf   = (unsigned short*)p; p += 1048576;   // [512][1024]
    unsigned short* wq_bf  = (unsigned short*)p; p += 2097152;   // [1024][1024]
    unsigned short* wkT_bf = (unsigned short*)p; p += 2097152;   // [2][1024][512]
    unsigned short* wv_bf  = (unsigned short*)p; p += 2097152;   // [1024][1024]
    unsigned short* wo_bf  = (unsigned short*)p; p += 2097152;   // [1024][1024]
    unsigned short* q_bf   = (unsigned short*)p; p += 1048576;   // [512][1024]
    unsigned short* sac_bf = (unsigned short*)p; p += 2097152;   // [512][2048]
    unsigned short* ctx_bf = (unsigned short*)p; p += 1048576;   // [512][1024]
    unsigned short* acat   = (unsigned short*)p; p += 3145728;   // [512][3072]
    unsigned short* wcat   = (unsigned short*)p; p += 25165824;  // [4096][3072]
    // overlay region: {qtl, spart, mlpart} (attention) / {gates} (after combine)
    char* ov = p;
    float*          qtl      = (float*)ov;                       // [512][2][1024] f32
    unsigned short* spart_bf = (unsigned short*)(ov + 4194304);  // [512][8][2][1024] bf16
    float*          mlpart   = (float*)(ov + 4194304 + 16777216);// [512][8][2][2]
    float*          gates    = (float*)ov;                       // [512][4096] (aliases, later)

    const float* wk_f = in_w + (long)kD * kD;
    const float* bq = in_b;
    const float* bv = in_b + 2 * kD;

    auto cvt = [&](const float* src, unsigned short* dst, int rows, int scols,
                   int dcols, int coloff) {
        int n8 = rows * (scols / 8);
        cvt_bf16<<<(n8 + 255) / 256, 256, 0, stream>>>(src, dst, scols / 8, dcols, coloff, n8);
    };

    // ---- conversions (proven 7-launch form)
    cvt(h, h_bf, 512, 1024, 1024, 0);
    cvt(in_w, wq_bf, 1024, 1024, 1024, 0);
    tcvt_wk<<<dim3(32, 16, 2), 256, 0, stream>>>(wk_f, wkT_bf);
    cvt(in_w + 2L * kD * kD, wv_bf, 1024, 1024, 1024, 0);
    cvt(wo, wo_bf, 1024, 1024, 1024, 0);
    cvt(w_ih, wcat, 4096, 2048, 3072, 0);
    cvt(w_hh, wcat, 4096, 1024, 3072, 2048);

    // 1. q_bf = bf16(h @ wq^T + bq)
    gemm64<<<dim3(16, 8, 1), 256, 0, stream>>>(
        h_bf, 1024, 0, wq_bf, 1024, 0,
        nullptr, 0, 0, q_bf, 1024, 0, bq, 0, 1024);

    // 2. qtl[:, z, :] = q_z @ wkT_z^T   (f32 out; scale pre-folded in wkT)
    gemm64<<<dim3(16, 8, 2), 256, 0, stream>>>(
        q_bf, 1024, 512, wkT_bf, 512, 524288,
        qtl, 2048, 1024, nullptr, 0, 0, nullptr, 0, 512);

    // 3. streaming attention -> partials (frozen; ~88% of achievable BW)
    attn7<<<kB, 512, 0, stream>>>(xall, qtl, spart_bf, mlpart);

    // 4. combine 8 partials -> sac_bf (bf16)
    attn_combine8<<<kB, 256, 0, stream>>>(spart_bf, mlpart, sac_bf);

    // 5. ctx_bf[:, z*512:] = bf16(s_z @ wv_z^T + bv_z)
    gemm64<<<dim3(8, 8, 2), 256, 0, stream>>>(
        sac_bf, 2048, 1024, wv_bf, 1024, 524288,
        nullptr, 0, 0, ctx_bf, 1024, 512, bv, 512, 1024);

    // 6. acat[:, 0:1024] = bf16(ctx @ wo^T + bo)
    gemm64<<<dim3(16, 8, 1), 256, 0, stream>>>(
        ctx_bf, 1024, 0, wo_bf, 1024, 0,
        nullptr, 0, 0, acat, 3072, 0, bo, 0, 1024);

    // remaining acat columns
    cvt(ext, acat, 512, 1024, 3072, 1024);
    cvt(h,   acat, 512, 1024, 3072, 2048);

    // 7. gates = acat @ wcat^T + b_ih + b_hh   (64x64 BK=64, 512 blocks = 2/CU)
    gemm_gates64<<<dim3(64, 8), 256, 0, stream>>>(
        acat, 3072, wcat, 3072, gates, 4096, b_ih, b_hh, 3072);

    // 8. LSTM cell + LayerNorm
    lstm_ln<<<kB, 256, 0, stream>>>(gates, c, ln_w, ln_b, out0, out1);
}

// Round 13
// 390.355 us; speedup vs baseline: 1.5468x; 1.0158x over previous
//
#include <hip/hip_runtime.h>
#include <math.h>
#include <stdint.h>

constexpr int kD  = 1024;   // model dim
constexpr int kB  = 512;    // batch
constexpr int kN  = 512;    // states per batch
constexpr int kDH = 512;    // head dim (H=2)

using bf16x8 = __attribute__((ext_vector_type(8))) short;
using f32x4v = __attribute__((ext_vector_type(4))) float;
using us8    = __attribute__((ext_vector_type(8))) unsigned short;
using us4    = __attribute__((ext_vector_type(4))) unsigned short;

__device__ __forceinline__ unsigned short f2bf(float f) {
    uint32_t u = __float_as_uint(f);
    u += 0x7fffu + ((u >> 16) & 1u);     // round-to-nearest-even
    return (unsigned short)(u >> 16);
}

__device__ __forceinline__ float bf2f(unsigned short s) {
    return __uint_as_float((uint32_t)s << 16);
}

__device__ __forceinline__ void async16(const void* g, void* l) {
    __builtin_amdgcn_global_load_lds(
        (const __attribute__((address_space(1))) uint32_t*)g,
        (__attribute__((address_space(3))) uint32_t*)l, 16, 0, 0);
}

// ---------------------------------------------------------------------------
// f32 -> bf16 convert (proven single-purpose form; mega-cvt BANNED:
// 3/3 crashes R4/R5/R11, 7/7 passes without).
// ---------------------------------------------------------------------------
__global__ __launch_bounds__(256)
void cvt_bf16(const float* __restrict__ src, unsigned short* __restrict__ dst,
              int scols8, int dcols, int coloff, int n8)
{
    int idx = blockIdx.x * 256 + threadIdx.x;
    if (idx >= n8) return;
    int row = idx / scols8;
    int c = (idx - row * scols8) * 8;
    const float4* s = (const float4*)(src + (long)row * ((long)scols8 * 8) + c);
    float4 v0 = s[0], v1 = s[1];
    us8 o;
    o[0] = f2bf(v0.x); o[1] = f2bf(v0.y); o[2] = f2bf(v0.z); o[3] = f2bf(v0.w);
    o[4] = f2bf(v1.x); o[5] = f2bf(v1.y); o[6] = f2bf(v1.z); o[7] = f2bf(v1.w);
    *(us8*)(dst + (long)row * dcols + coloff + c) = o;
}

// ---------------------------------------------------------------------------
// wk transpose+convert with SCALE FOLDED IN (proven).
// ---------------------------------------------------------------------------
__global__ __launch_bounds__(256)
void tcvt_wk(const float* __restrict__ wk, unsigned short* __restrict__ dst)
{
    __shared__ float t[32][33];
    const int nt = blockIdx.x;     // 0..31 (n tiles)
    const int kt = blockIdx.y;     // 0..15 (k tiles)
    const int hh = blockIdx.z;     // head
    const int tx = threadIdx.x & 31, ty = threadIdx.x >> 5;   // 32 x 8
    const float scale = 0.044194173824159216f;   // 1/sqrt(512)
#pragma unroll
    for (int j = 0; j < 4; ++j)
        t[ty + j * 8][tx] = wk[(long)(hh * 512 + kt * 32 + ty + j * 8) * kD + nt * 32 + tx];
    __syncthreads();
#pragma unroll
    for (int j = 0; j < 4; ++j) {
        int n = nt * 32 + ty + j * 8;
        int k = kt * 32 + tx;
        dst[(long)hh * 524288 + (long)n * 512 + k] = f2bf(t[tx][ty + j * 8] * scale);
    }
}

// ---------------------------------------------------------------------------
// gemm32: bf16 MFMA GEMM, NT, 32x64 tile, BK=32, 256 threads (4 waves:
// 2 M-halves x 2 N-halves, 16x32 each). Same staging/compute/epilogue
// skeleton as the proven gemm64 at half tile-height -> 2x the blocks for
// M=512-shaped GEMMs (full-chip grids instead of half-idle).
// ---------------------------------------------------------------------------
__global__ __launch_bounds__(256)
void gemm32(const unsigned short* __restrict__ A, int lda, long sAz,
            const unsigned short* __restrict__ B, int ldb, long sBz,
            float* __restrict__ Cf, int ldcf, long sCfz,
            unsigned short* __restrict__ Cb, int ldcb, long sCbz,
            const float* __restrict__ bias, long sbz, int K)
{
    __shared__ short As[4][32][8];
    __shared__ short Bs[4][64][8];
    A += (long)blockIdx.z * sAz;
    B += (long)blockIdx.z * sBz;

    const int tid = threadIdx.x;
    const int l = tid & 63, w = tid >> 6;
    const int wr = w >> 1, wc = w & 1;
    const int bm = blockIdx.y * 32, bn = blockIdx.x * 64;

    f32x4v acc[2] = {};

    for (int k0 = 0; k0 < K; k0 += 32) {
        __syncthreads();
        if (tid < 128) {
            int ks = tid >> 5, r = tid & 31;
            async16(A + (long)(bm + r) * lda + k0 + ks * 8, (short*)As + (long)tid * 8);
        }
        {
            int ks = tid >> 6, r = tid & 63;
            async16(B + (long)(bn + r) * ldb + k0 + ks * 8, (short*)Bs + (long)tid * 8);
        }
        __syncthreads();   // vmcnt drained before barrier (m97 pattern)

        const int ks = l >> 4, rr = l & 15;
        bf16x8 a  = *(const bf16x8*)&As[ks][wr * 16 + rr][0];
        bf16x8 b0 = *(const bf16x8*)&Bs[ks][wc * 32 + rr][0];
        bf16x8 b1 = *(const bf16x8*)&Bs[ks][wc * 32 + 16 + rr][0];
        acc[0] = __builtin_amdgcn_mfma_f32_16x16x32_bf16(a, b0, acc[0], 0, 0, 0);
        acc[1] = __builtin_amdgcn_mfma_f32_16x16x32_bf16(a, b1, acc[1], 0, 0, 0);
    }

    const int rr = l & 15, rg = l >> 4;
#pragma unroll
    for (int nt = 0; nt < 2; ++nt) {
        const int n = bn + wc * 32 + nt * 16 + rr;
        float bb = bias ? bias[(long)blockIdx.z * sbz + n] : 0.f;
#pragma unroll
        for (int r = 0; r < 4; ++r) {
            const int m = bm + wr * 16 + rg * 4 + r;
            float val = acc[nt][r] + bb;
            if (Cf) Cf[(long)blockIdx.z * sCfz + (long)m * ldcf + n] = val;
            if (Cb) Cb[(long)blockIdx.z * sCbz + (long)m * ldcb + n] = f2bf(val);
        }
    }
}

// ---------------------------------------------------------------------------
// gemm_gates_sk: split-K gates GEMM. 64x64 tile, BK=64, blockIdx.z picks
// K-half [z*1536, z*1536+1536). 1024 blocks = 4/CU, 16 waves/CU.
// No bias (added in lstm_ln2 with the partial sum). Proven R12 skeleton.
// ---------------------------------------------------------------------------
__global__ __launch_bounds__(256)
void gemm_gates_sk(const unsigned short* __restrict__ A, int lda,
                   const unsigned short* __restrict__ B, int ldb,
                   float* __restrict__ Cf, int ldcf, long sCfz)
{
    __shared__ short As[8][64][8];
    __shared__ short Bs[8][64][8];

    const int tid = threadIdx.x;
    const int l = tid & 63, w = tid >> 6;
    const int wr = w >> 1, wc = w & 1;
    const int bm = blockIdx.y * 64, bn = blockIdx.x * 64;
    const int kbase = blockIdx.z * 1536;

    f32x4v acc[2][2] = {};

    for (int k0 = 0; k0 < 1536; k0 += 64) {
        __syncthreads();
#pragma unroll
        for (int j = 0; j < 2; ++j) {
            int ca = j * 256 + tid;            // 0..511: ks 0..7, row 0..63
            int ks = ca >> 6, r = ca & 63;
            async16(A + (long)(bm + r) * lda + kbase + k0 + ks * 8, (short*)As + (long)ca * 8);
            async16(B + (long)(bn + r) * ldb + kbase + k0 + ks * 8, (short*)Bs + (long)ca * 8);
        }
        __syncthreads();   // vmcnt drained before barrier (m97 pattern)

        const int ksl = l >> 4, rr = l & 15;
#pragma unroll
        for (int p = 0; p < 2; ++p) {
            bf16x8 a[2], b[2];
#pragma unroll
            for (int t = 0; t < 2; ++t) {
                a[t] = *(const bf16x8*)&As[p * 4 + ksl][wr * 32 + t * 16 + rr][0];
                b[t] = *(const bf16x8*)&Bs[p * 4 + ksl][wc * 32 + t * 16 + rr][0];
            }
#pragma unroll
            for (int mt = 0; mt < 2; ++mt)
#pragma unroll
                for (int nt = 0; nt < 2; ++nt)
                    acc[mt][nt] = __builtin_amdgcn_mfma_f32_16x16x32_bf16(
                        a[mt], b[nt], acc[mt][nt], 0, 0, 0);
        }
    }

    const int rr = l & 15, rg = l >> 4;
    float* Cz = Cf + (long)blockIdx.z * sCfz;
#pragma unroll
    for (int mt = 0; mt < 2; ++mt) {
#pragma unroll
        for (int nt = 0; nt < 2; ++nt) {
            const int n = bn + wc * 32 + nt * 16 + rr;
#pragma unroll
            for (int r = 0; r < 4; ++r) {
                const int m = bm + wr * 32 + mt * 16 + rg * 4 + r;
                Cz[(long)m * ldcf + n] = acc[mt][nt][r];
            }
        }
    }
}

// ---------------------------------------------------------------------------
// attn7 (proven; R10-measured 195 us = ~88% of achievable HBM BW — frozen).
// ---------------------------------------------------------------------------
__global__ __launch_bounds__(512, 4)
void attn7(const float* __restrict__ xall,        // [B][N][D] f32
           const float* __restrict__ qt,          // [B][2][D] f32 (pre-scaled)
           unsigned short* __restrict__ spart_bf, // [B][8][2][1024] bf16
           float* __restrict__ mlpart)            // [B][8][2][2] f32
{
    const int b = blockIdx.x;
    const int tid = threadIdx.x;
    const int w = tid >> 6, l = tid & 63;

    float qa[16], qb[16];
    {
        const float* qp = qt + (long)b * 2048 + l * 4;
#pragma unroll
        for (int q = 0; q < 4; ++q) {
            float4 v0 = *(const float4*)(qp + q * 256);
            float4 v1 = *(const float4*)(qp + 1024 + q * 256);
            qa[q*4+0] = v0.x; qa[q*4+1] = v0.y; qa[q*4+2] = v0.z; qa[q*4+3] = v0.w;
            qb[q*4+0] = v1.x; qb[q*4+1] = v1.y; qb[q*4+2] = v1.z; qb[q*4+3] = v1.w;
        }
    }

    float m0 = -1e30f, l0 = 0.f, m1 = -1e30f, l1 = 0.f;
    float sa[16] = {}, sb[16] = {};

    const float* xr = xall + ((long)b * kN + w * 64) * kD + l * 4;

    for (int r = 0; r < 64; ++r) {
        float xv[16];
#pragma unroll
        for (int q = 0; q < 4; ++q) {
            float4 v = *(const float4*)(xr + q * 256);
            xv[q*4+0] = v.x; xv[q*4+1] = v.y; xv[q*4+2] = v.z; xv[q*4+3] = v.w;
        }
        xr += kD;

        float c0=0.f,c1=0.f,c2=0.f,c3=0.f, e0=0.f,e1=0.f,e2=0.f,e3=0.f;
#pragma unroll
        for (int q = 0; q < 4; ++q) {
            c0 += xv[q*4+0]*qa[q*4+0]; c1 += xv[q*4+1]*qa[q*4+1];
            c2 += xv[q*4+2]*qa[q*4+2]; c3 += xv[q*4+3]*qa[q*4+3];
            e0 += xv[q*4+0]*qb[q*4+0]; e1 += xv[q*4+1]*qb[q*4+1];
            e2 += xv[q*4+2]*qb[q*4+2]; e3 += xv[q*4+3]*qb[q*4+3];
        }
        float d0 = (c0 + c1) + (c2 + c3);
        float d1 = (e0 + e1) + (e2 + e3);
#pragma unroll
        for (int mm = 32; mm >= 1; mm >>= 1) {
            d0 += __shfl_xor(d0, mm);
            d1 += __shfl_xor(d1, mm);
        }

        if (d0 > m0 + 8.f) {                       // defer-max (T13), uniform
            float rsc = __expf(m0 - d0);
            l0 *= rsc;
#pragma unroll
            for (int j = 0; j < 16; ++j) sa[j] *= rsc;
            m0 = d0;
        }
        float p0 = __expf(d0 - m0);
        l0 += p0;

        if (d1 > m1 + 8.f) {
            float rsc = __expf(m1 - d1);
            l1 *= rsc;
#pragma unroll
            for (int j = 0; j < 16; ++j) sb[j] *= rsc;
            m1 = d1;
        }
        float p1 = __expf(d1 - m1);
        l1 += p1;

#pragma unroll
        for (int j = 0; j < 16; ++j) {
            sa[j] += p0 * xv[j];
            sb[j] += p1 * xv[j];
        }
    }

    unsigned short* sp0 = spart_bf + (((long)b * 8 + w) * 2 + 0) * 1024 + l * 4;
    unsigned short* sp1 = spart_bf + (((long)b * 8 + w) * 2 + 1) * 1024 + l * 4;
#pragma unroll
    for (int q = 0; q < 4; ++q) {
        us4 o0, o1;
        o0[0] = f2bf(sa[q*4+0]); o0[1] = f2bf(sa[q*4+1]);
        o0[2] = f2bf(sa[q*4+2]); o0[3] = f2bf(sa[q*4+3]);
        o1[0] = f2bf(sb[q*4+0]); o1[1] = f2bf(sb[q*4+1]);
        o1[2] = f2bf(sb[q*4+2]); o1[3] = f2bf(sb[q*4+3]);
        *(us4*)(sp0 + q * 256) = o0;
        *(us4*)(sp1 + q * 256) = o1;
    }

    if (l == 0) {
        float* mlp = mlpart + (((long)b * 8 + w) * 2) * 2;
        mlp[0] = m0; mlp[1] = l0; mlp[2] = m1; mlp[3] = l1;
    }
}

// ---------------------------------------------------------------------------
// Combine 8 per-wave partials -> normalized sums (proven).
// ---------------------------------------------------------------------------
__global__ __launch_bounds__(256)
void attn_combine8(const unsigned short* __restrict__ spart_bf,
                   const float* __restrict__ mlpart,
                   unsigned short* __restrict__ sac_bf)
{
    const int b = blockIdx.x;
    const int tid = threadIdx.x;
    const int h = tid >> 7, d0 = (tid & 127) * 8;

    float m[8], lv[8];
#pragma unroll
    for (int c = 0; c < 8; ++c) {
        const float* mlp = mlpart + (((long)b * 8 + c) * 2 + h) * 2;
        m[c] = mlp[0]; lv[c] = mlp[1];
    }
    float ms = m[0];
#pragma unroll
    for (int c = 1; c < 8; ++c) ms = fmaxf(ms, m[c]);
    float wgt[8], L = 0.f;
#pragma unroll
    for (int c = 0; c < 8; ++c) { wgt[c] = __expf(m[c] - ms); L += wgt[c] * lv[c]; }
    const float inv = 1.0f / L;

    float acc[8] = {};
#pragma unroll
    for (int c = 0; c < 8; ++c) {
        us8 sv = *(const us8*)(spart_bf + (((long)b * 8 + c) * 2 + h) * 1024 + d0);
#pragma unroll
        for (int j = 0; j < 8; ++j)
            acc[j] += wgt[c] * bf2f(sv[j]);
    }
    us8 o;
#pragma unroll
    for (int j = 0; j < 8; ++j) o[j] = f2bf(acc[j] * inv);
    *(us8*)(sac_bf + (long)b * 2048 + h * kD + d0) = o;
}

// ---------------------------------------------------------------------------
// Fused LSTM cell + LayerNorm, reading TWO gate partials + both biases.
// ---------------------------------------------------------------------------
__device__ __forceinline__ float sigm(float x) { return 1.0f / (1.0f + __expf(-x)); }

__global__ __launch_bounds__(256)
void lstm_ln2(const float* __restrict__ gA, const float* __restrict__ gB,
              const float* __restrict__ b_ih, const float* __restrict__ b_hh,
              const float* __restrict__ cin,
              const float* __restrict__ ln_w, const float* __restrict__ ln_b,
              float* __restrict__ out0, float* __restrict__ out1)
{
    __shared__ float red[2][4];
    __shared__ float stats[2];

    const int b = blockIdx.x;
    const int tid = threadIdx.x;
    const int d4 = tid * 4;
    const float* ga = gA + (long)b * 4096;
    const float* gb = gB + (long)b * 4096;

    float iv[4], fv[4], gv[4], ov[4];
#pragma unroll
    for (int gidx = 0; gidx < 4; ++gidx) {
        const int off = gidx * 1024 + d4;
        float4 a = *(const float4*)(ga + off);
        float4 bq = *(const float4*)(gb + off);
        float4 bi = *(const float4*)(b_ih + off);
        float4 bh = *(const float4*)(b_hh + off);
        float* dstv = (gidx == 0) ? iv : (gidx == 1) ? fv : (gidx == 2) ? gv : ov;
        dstv[0] = a.x + bq.x + bi.x + bh.x;
        dstv[1] = a.y + bq.y + bi.y + bh.y;
        dstv[2] = a.z + bq.z + bi.z + bh.z;
        dstv[3] = a.w + bq.w + bi.w + bh.w;
    }
    float4 cv = *(const float4*)(cin + (long)b * kD + d4);
    float cc[4] = {cv.x, cv.y, cv.z, cv.w};

    float nc[4], nh[4];
#pragma unroll
    for (int u = 0; u < 4; ++u) {
        nc[u] = sigm(fv[u]) * cc[u] + sigm(iv[u]) * tanhf(gv[u]);
        nh[u] = sigm(ov[u]) * tanhf(nc[u]);
    }
    *(float4*)(out1 + (long)b * kD + d4) = make_float4(nc[0], nc[1], nc[2], nc[3]);

    float sum = nh[0] + nh[1] + nh[2] + nh[3];
    float ss  = nh[0]*nh[0] + nh[1]*nh[1] + nh[2]*nh[2] + nh[3]*nh[3];
#pragma unroll
    for (int m = 32; m >= 1; m >>= 1) {
        sum += __shfl_xor(sum, m);
        ss  += __shfl_xor(ss, m);
    }
    const int wave = tid >> 6, lane = tid & 63;
    if (lane == 0) { red[0][wave] = sum; red[1][wave] = ss; }
    __syncthreads();
    if (tid == 0) {
        float s = red[0][0] + red[0][1] + red[0][2] + red[0][3];
        float q = red[1][0] + red[1][1] + red[1][2] + red[1][3];
        float mu = s / (float)kD;
        float var = q / (float)kD - mu * mu;
        stats[0] = mu;
        stats[1] = rsqrtf(var + 1e-5f);
    }
    __syncthreads();
    const float mu = stats[0], rstd = stats[1];
    float4 lw = *(const float4*)(ln_w + d4);
    float4 lb = *(const float4*)(ln_b + d4);
    float lwv[4] = {lw.x, lw.y, lw.z, lw.w};
    float lbv[4] = {lb.x, lb.y, lb.z, lb.w};
    float o[4];
#pragma unroll
    for (int u = 0; u < 4; ++u)
        o[u] = (nh[u] - mu) * rstd * lwv[u] + lbv[u];
    *(float4*)(out0 + (long)b * kD + d4) = make_float4(o[0], o[1], o[2], o[3]);
}

// ---------------------------------------------------------------------------
extern "C" void kernel_launch(void* const* d_in, const int* in_sizes, int n_in,
                              void* d_out, int out_size, void* d_ws, size_t ws_size,
                              hipStream_t stream)
{
    (void)in_sizes; (void)n_in; (void)out_size;

    const float* h    = (const float*)d_in[0];
    const float* c    = (const float*)d_in[1];
    const float* xall = (const float*)d_in[2];
    const float* ext  = (const float*)d_in[3];
    const float* in_w = (const float*)d_in[4];
    const float* in_b = (const float*)d_in[5];
    const float* wo   = (const float*)d_in[6];
    const float* bo   = (const float*)d_in[7];
    const float* w_ih = (const float*)d_in[8];
    const float* b_ih = (const float*)d_in[9];
    const float* w_hh = (const float*)d_in[10];
    const float* b_hh = (const float*)d_in[11];
    const float* ln_w = (const float*)d_in[12];
    const float* ln_b = (const float*)d_in[13];

    float* out0 = (float*)d_out;              // LN(new_h) [512x1024]
    float* out1 = out0 + (long)kB * kD;       // new_c     [512x1024]

    // ---- workspace layout (identical offsets to round 8/12)
    char* p = (char*)d_ws;
    const size_t need = 63062016ull;
    if (ws_size < need) return;

    p += 16384;                                                  // (spare)
    unsigned short* h_bf   = (unsigned short*)p; p += 1048576;   // [512][1024]
    unsigned short* wq_bf  = (unsigned short*)p; p += 2097152;   // [1024][1024]
    unsigned short* wkT_bf = (unsigned short*)p; p += 2097152;   // [2][1024][512]
    unsigned short* wv_bf  = (unsigned short*)p; p += 2097152;   // [1024][1024]
    unsigned short* wo_bf  = (unsigned short*)p; p += 2097152;   // [1024][1024]
    unsigned short* q_bf   = (unsigned short*)p; p += 1048576;   // [512][1024]
    unsigned short* sac_bf = (unsigned short*)p; p += 2097152;   // [512][2048]
    unsigned short* ctx_bf = (unsigned short*)p; p += 1048576;   // [512][1024]
    unsigned short* acat   = (unsigned short*)p; p += 3145728;   // [512][3072]
    unsigned short* wcat   = (unsigned short*)p; p += 25165824;  // [4096][3072]
    // overlay region: {qtl, spart, mlpart} (attention) / {gatesA,B} (later)
    char* ov = p;
    float*          qtl      = (float*)ov;                       // [512][2][1024] f32
    unsigned short* spart_bf = (unsigned short*)(ov + 4194304);  // [512][8][2][1024] bf16
    float*          mlpart   = (float*)(ov + 4194304 + 16777216);// [512][8][2][2]
    float*          gatesA   = (float*)ov;                       // [512][4096] f32
    float*          gatesB   = (float*)(ov + 8388608);           // [512][4096] f32

    const float* wk_f = in_w + (long)kD * kD;
    const float* bq = in_b;
    const float* bv = in_b + 2 * kD;

    auto cvt = [&](const float* src, unsigned short* dst, int rows, int scols,
                   int dcols, int coloff) {
        int n8 = rows * (scols / 8);
        cvt_bf16<<<(n8 + 255) / 256, 256, 0, stream>>>(src, dst, scols / 8, dcols, coloff, n8);
    };

    // ---- conversions (proven 7-launch form)
    cvt(h, h_bf, 512, 1024, 1024, 0);
    cvt(in_w, wq_bf, 1024, 1024, 1024, 0);
    tcvt_wk<<<dim3(32, 16, 2), 256, 0, stream>>>(wk_f, wkT_bf);
    cvt(in_w + 2L * kD * kD, wv_bf, 1024, 1024, 1024, 0);
    cvt(wo, wo_bf, 1024, 1024, 1024, 0);
    cvt(w_ih, wcat, 4096, 2048, 3072, 0);
    cvt(w_hh, wcat, 4096, 1024, 3072, 2048);

    // 1. q_bf = bf16(h @ wq^T + bq)   (32x64 tiles: 256 blocks, full chip)
    gemm32<<<dim3(16, 16, 1), 256, 0, stream>>>(
        h_bf, 1024, 0, wq_bf, 1024, 0,
        nullptr, 0, 0, q_bf, 1024, 0, bq, 0, 1024);

    // 2. qtl[:, z, :] = q_z @ wkT_z^T   (512 blocks)
    gemm32<<<dim3(16, 16, 2), 256, 0, stream>>>(
        q_bf, 1024, 512, wkT_bf, 512, 524288,
        qtl, 2048, 1024, nullptr, 0, 0, nullptr, 0, 512);

    // 3. streaming attention -> partials (frozen; ~88% of achievable BW)
    attn7<<<kB, 512, 0, stream>>>(xall, qtl, spart_bf, mlpart);

    // 4. combine 8 partials -> sac_bf (bf16)
    attn_combine8<<<kB, 256, 0, stream>>>(spart_bf, mlpart, sac_bf);

    // 5. ctx_bf[:, z*512:] = bf16(s_z @ wv_z^T + bv_z)   (256 blocks)
    gemm32<<<dim3(8, 16, 2), 256, 0, stream>>>(
        sac_bf, 2048, 1024, wv_bf, 1024, 524288,
        nullptr, 0, 0, ctx_bf, 1024, 512, bv, 512, 1024);

    // 6. acat[:, 0:1024] = bf16(ctx @ wo^T + bo)   (256 blocks)
    gemm32<<<dim3(16, 16, 1), 256, 0, stream>>>(
        ctx_bf, 1024, 0, wo_bf, 1024, 0,
        nullptr, 0, 0, acat, 3072, 0, bo, 0, 1024);

    // remaining acat columns
    cvt(ext, acat, 512, 1024, 3072, 1024);
    cvt(h,   acat, 512, 1024, 3072, 2048);

    // 7. gates partials = acat @ wcat^T, K split 2x (1024 blocks = 4/CU)
    gemm_gates_sk<<<dim3(64, 8, 2), 256, 0, stream>>>(
        acat, 3072, wcat, 3072, gatesA, 4096, 2097152);

    // 8. LSTM cell (gatesA+gatesB+b_ih+b_hh) + LayerNorm
    lstm_ln2<<<kB, 256, 0, stream>>>(gatesA, gatesB, b_ih, b_hh,
                                     c, ln_w, ln_b, out0, out1);
}

// Round 14
// 383.087 us; speedup vs baseline: 1.5761x; 1.0190x over previous
//
#include <hip/hip_runtime.h>
#include <math.h>
#include <stdint.h>

constexpr int kD  = 1024;   // model dim
constexpr int kB  = 512;    // batch
constexpr int kN  = 512;    // states per batch
constexpr int kDH = 512;    // head dim (H=2)

using bf16x8 = __attribute__((ext_vector_type(8))) short;
using f32x4v = __attribute__((ext_vector_type(4))) float;
using us8    = __attribute__((ext_vector_type(8))) unsigned short;
using us4    = __attribute__((ext_vector_type(4))) unsigned short;

__device__ __forceinline__ unsigned short f2bf(float f) {
    uint32_t u = __float_as_uint(f);
    u += 0x7fffu + ((u >> 16) & 1u);     // round-to-nearest-even
    return (unsigned short)(u >> 16);
}

__device__ __forceinline__ float bf2f(unsigned short s) {
    return __uint_as_float((uint32_t)s << 16);
}

__device__ __forceinline__ void async16(const void* g, void* l) {
    __builtin_amdgcn_global_load_lds(
        (const __attribute__((address_space(1))) uint32_t*)g,
        (__attribute__((address_space(3))) uint32_t*)l, 16, 0, 0);
}

// ---------------------------------------------------------------------------
// f32 -> bf16 convert (proven single-purpose form; mega-cvt BANNED:
// 3/3 crashes R4/R5/R11, 7/7 passes without).
// ---------------------------------------------------------------------------
__global__ __launch_bounds__(256)
void cvt_bf16(const float* __restrict__ src, unsigned short* __restrict__ dst,
              int scols8, int dcols, int coloff, int n8)
{
    int idx = blockIdx.x * 256 + threadIdx.x;
    if (idx >= n8) return;
    int row = idx / scols8;
    int c = (idx - row * scols8) * 8;
    const float4* s = (const float4*)(src + (long)row * ((long)scols8 * 8) + c);
    float4 v0 = s[0], v1 = s[1];
    us8 o;
    o[0] = f2bf(v0.x); o[1] = f2bf(v0.y); o[2] = f2bf(v0.z); o[3] = f2bf(v0.w);
    o[4] = f2bf(v1.x); o[5] = f2bf(v1.y); o[6] = f2bf(v1.z); o[7] = f2bf(v1.w);
    *(us8*)(dst + (long)row * dcols + coloff + c) = o;
}

// ---------------------------------------------------------------------------
// wk transpose+convert with SCALE FOLDED IN (proven).
// ---------------------------------------------------------------------------
__global__ __launch_bounds__(256)
void tcvt_wk(const float* __restrict__ wk, unsigned short* __restrict__ dst)
{
    __shared__ float t[32][33];
    const int nt = blockIdx.x;     // 0..31 (n tiles)
    const int kt = blockIdx.y;     // 0..15 (k tiles)
    const int hh = blockIdx.z;     // head
    const int tx = threadIdx.x & 31, ty = threadIdx.x >> 5;   // 32 x 8
    const float scale = 0.044194173824159216f;   // 1/sqrt(512)
#pragma unroll
    for (int j = 0; j < 4; ++j)
        t[ty + j * 8][tx] = wk[(long)(hh * 512 + kt * 32 + ty + j * 8) * kD + nt * 32 + tx];
    __syncthreads();
#pragma unroll
    for (int j = 0; j < 4; ++j) {
        int n = nt * 32 + ty + j * 8;
        int k = kt * 32 + tx;
        dst[(long)hh * 524288 + (long)n * 512 + k] = f2bf(t[tx][ty + j * 8] * scale);
    }
}

// ---------------------------------------------------------------------------
// gemm32: bf16 MFMA GEMM, NT, 32x64 tile, now BK=64 (halved K iterations:
// each barrier drain amortizes 2x the MFMA work). 256 threads, 4 waves.
// Staging: As = 1 async16/thread, Bs = 2 async16/thread. LDS 12 KB.
// ---------------------------------------------------------------------------
__global__ __launch_bounds__(256)
void gemm32(const unsigned short* __restrict__ A, int lda, long sAz,
            const unsigned short* __restrict__ B, int ldb, long sBz,
            float* __restrict__ Cf, int ldcf, long sCfz,
            unsigned short* __restrict__ Cb, int ldcb, long sCbz,
            const float* __restrict__ bias, long sbz, int K)
{
    __shared__ short As[8][32][8];   // 4 KB
    __shared__ short Bs[8][64][8];   // 8 KB
    A += (long)blockIdx.z * sAz;
    B += (long)blockIdx.z * sBz;

    const int tid = threadIdx.x;
    const int l = tid & 63, w = tid >> 6;
    const int wr = w >> 1, wc = w & 1;
    const int bm = blockIdx.y * 32, bn = blockIdx.x * 64;

    f32x4v acc[2] = {};

    for (int k0 = 0; k0 < K; k0 += 64) {
        __syncthreads();
        {
            int ks = tid >> 5, r = tid & 31;     // ks 0..7, r 0..31
            async16(A + (long)(bm + r) * lda + k0 + ks * 8, (short*)As + (long)tid * 8);
        }
#pragma unroll
        for (int j = 0; j < 2; ++j) {
            int ca = j * 256 + tid;              // 0..511: ks 0..7, r 0..63
            int ks = ca >> 6, r = ca & 63;
            async16(B + (long)(bn + r) * ldb + k0 + ks * 8, (short*)Bs + (long)ca * 8);
        }
        __syncthreads();   // vmcnt drained before barrier (m97 pattern)

        const int ksl = l >> 4, rr = l & 15;
#pragma unroll
        for (int p = 0; p < 2; ++p) {
            bf16x8 a  = *(const bf16x8*)&As[p * 4 + ksl][wr * 16 + rr][0];
            bf16x8 b0 = *(const bf16x8*)&Bs[p * 4 + ksl][wc * 32 + rr][0];
            bf16x8 b1 = *(const bf16x8*)&Bs[p * 4 + ksl][wc * 32 + 16 + rr][0];
            acc[0] = __builtin_amdgcn_mfma_f32_16x16x32_bf16(a, b0, acc[0], 0, 0, 0);
            acc[1] = __builtin_amdgcn_mfma_f32_16x16x32_bf16(a, b1, acc[1], 0, 0, 0);
        }
    }

    const int rr = l & 15, rg = l >> 4;
#pragma unroll
    for (int nt = 0; nt < 2; ++nt) {
        const int n = bn + wc * 32 + nt * 16 + rr;
        float bb = bias ? bias[(long)blockIdx.z * sbz + n] : 0.f;
#pragma unroll
        for (int r = 0; r < 4; ++r) {
            const int m = bm + wr * 16 + rg * 4 + r;
            float val = acc[nt][r] + bb;
            if (Cf) Cf[(long)blockIdx.z * sCfz + (long)m * ldcf + n] = val;
            if (Cb) Cb[(long)blockIdx.z * sCbz + (long)m * ldcb + n] = f2bf(val);
        }
    }
}

// ---------------------------------------------------------------------------
// gemm_gates_sk: split-K gates GEMM (proven R13). 64x64 tile, BK=64,
// blockIdx.z picks K-half. 1024 blocks = 4/CU, 16 waves/CU.
// ---------------------------------------------------------------------------
__global__ __launch_bounds__(256)
void gemm_gates_sk(const unsigned short* __restrict__ A, int lda,
                   const unsigned short* __restrict__ B, int ldb,
                   float* __restrict__ Cf, int ldcf, long sCfz)
{
    __shared__ short As[8][64][8];
    __shared__ short Bs[8][64][8];

    const int tid = threadIdx.x;
    const int l = tid & 63, w = tid >> 6;
    const int wr = w >> 1, wc = w & 1;
    const int bm = blockIdx.y * 64, bn = blockIdx.x * 64;
    const int kbase = blockIdx.z * 1536;

    f32x4v acc[2][2] = {};

    for (int k0 = 0; k0 < 1536; k0 += 64) {
        __syncthreads();
#pragma unroll
        for (int j = 0; j < 2; ++j) {
            int ca = j * 256 + tid;            // 0..511: ks 0..7, row 0..63
            int ks = ca >> 6, r = ca & 63;
            async16(A + (long)(bm + r) * lda + kbase + k0 + ks * 8, (short*)As + (long)ca * 8);
            async16(B + (long)(bn + r) * ldb + kbase + k0 + ks * 8, (short*)Bs + (long)ca * 8);
        }
        __syncthreads();   // vmcnt drained before barrier (m97 pattern)

        const int ksl = l >> 4, rr = l & 15;
#pragma unroll
        for (int p = 0; p < 2; ++p) {
            bf16x8 a[2], b[2];
#pragma unroll
            for (int t = 0; t < 2; ++t) {
                a[t] = *(const bf16x8*)&As[p * 4 + ksl][wr * 32 + t * 16 + rr][0];
                b[t] = *(const bf16x8*)&Bs[p * 4 + ksl][wc * 32 + t * 16 + rr][0];
            }
#pragma unroll
            for (int mt = 0; mt < 2; ++mt)
#pragma unroll
                for (int nt = 0; nt < 2; ++nt)
                    acc[mt][nt] = __builtin_amdgcn_mfma_f32_16x16x32_bf16(
                        a[mt], b[nt], acc[mt][nt], 0, 0, 0);
        }
    }

    const int rr = l & 15, rg = l >> 4;
    float* Cz = Cf + (long)blockIdx.z * sCfz;
#pragma unroll
    for (int mt = 0; mt < 2; ++mt) {
#pragma unroll
        for (int nt = 0; nt < 2; ++nt) {
            const int n = bn + wc * 32 + nt * 16 + rr;
#pragma unroll
            for (int r = 0; r < 4; ++r) {
                const int m = bm + wr * 32 + mt * 16 + rg * 4 + r;
                Cz[(long)m * ldcf + n] = acc[mt][nt][r];
            }
        }
    }
}

// ---------------------------------------------------------------------------
// attn7 (proven; R10-measured 195 us = ~88% of achievable HBM BW — frozen).
// ---------------------------------------------------------------------------
__global__ __launch_bounds__(512, 4)
void attn7(const float* __restrict__ xall,        // [B][N][D] f32
           const float* __restrict__ qt,          // [B][2][D] f32 (pre-scaled)
           unsigned short* __restrict__ spart_bf, // [B][8][2][1024] bf16
           float* __restrict__ mlpart)            // [B][8][2][2] f32
{
    const int b = blockIdx.x;
    const int tid = threadIdx.x;
    const int w = tid >> 6, l = tid & 63;

    float qa[16], qb[16];
    {
        const float* qp = qt + (long)b * 2048 + l * 4;
#pragma unroll
        for (int q = 0; q < 4; ++q) {
            float4 v0 = *(const float4*)(qp + q * 256);
            float4 v1 = *(const float4*)(qp + 1024 + q * 256);
            qa[q*4+0] = v0.x; qa[q*4+1] = v0.y; qa[q*4+2] = v0.z; qa[q*4+3] = v0.w;
            qb[q*4+0] = v1.x; qb[q*4+1] = v1.y; qb[q*4+2] = v1.z; qb[q*4+3] = v1.w;
        }
    }

    float m0 = -1e30f, l0 = 0.f, m1 = -1e30f, l1 = 0.f;
    float sa[16] = {}, sb[16] = {};

    const float* xr = xall + ((long)b * kN + w * 64) * kD + l * 4;

    for (int r = 0; r < 64; ++r) {
        float xv[16];
#pragma unroll
        for (int q = 0; q < 4; ++q) {
            float4 v = *(const float4*)(xr + q * 256);
            xv[q*4+0] = v.x; xv[q*4+1] = v.y; xv[q*4+2] = v.z; xv[q*4+3] = v.w;
        }
        xr += kD;

        float c0=0.f,c1=0.f,c2=0.f,c3=0.f, e0=0.f,e1=0.f,e2=0.f,e3=0.f;
#pragma unroll
        for (int q = 0; q < 4; ++q) {
            c0 += xv[q*4+0]*qa[q*4+0]; c1 += xv[q*4+1]*qa[q*4+1];
            c2 += xv[q*4+2]*qa[q*4+2]; c3 += xv[q*4+3]*qa[q*4+3];
            e0 += xv[q*4+0]*qb[q*4+0]; e1 += xv[q*4+1]*qb[q*4+1];
            e2 += xv[q*4+2]*qb[q*4+2]; e3 += xv[q*4+3]*qb[q*4+3];
        }
        float d0 = (c0 + c1) + (c2 + c3);
        float d1 = (e0 + e1) + (e2 + e3);
#pragma unroll
        for (int mm = 32; mm >= 1; mm >>= 1) {
            d0 += __shfl_xor(d0, mm);
            d1 += __shfl_xor(d1, mm);
        }

        if (d0 > m0 + 8.f) {                       // defer-max (T13), uniform
            float rsc = __expf(m0 - d0);
            l0 *= rsc;
#pragma unroll
            for (int j = 0; j < 16; ++j) sa[j] *= rsc;
            m0 = d0;
        }
        float p0 = __expf(d0 - m0);
        l0 += p0;

        if (d1 > m1 + 8.f) {
            float rsc = __expf(m1 - d1);
            l1 *= rsc;
#pragma unroll
            for (int j = 0; j < 16; ++j) sb[j] *= rsc;
            m1 = d1;
        }
        float p1 = __expf(d1 - m1);
        l1 += p1;

#pragma unroll
        for (int j = 0; j < 16; ++j) {
            sa[j] += p0 * xv[j];
            sb[j] += p1 * xv[j];
        }
    }

    unsigned short* sp0 = spart_bf + (((long)b * 8 + w) * 2 + 0) * 1024 + l * 4;
    unsigned short* sp1 = spart_bf + (((long)b * 8 + w) * 2 + 1) * 1024 + l * 4;
#pragma unroll
    for (int q = 0; q < 4; ++q) {
        us4 o0, o1;
        o0[0] = f2bf(sa[q*4+0]); o0[1] = f2bf(sa[q*4+1]);
        o0[2] = f2bf(sa[q*4+2]); o0[3] = f2bf(sa[q*4+3]);
        o1[0] = f2bf(sb[q*4+0]); o1[1] = f2bf(sb[q*4+1]);
        o1[2] = f2bf(sb[q*4+2]); o1[3] = f2bf(sb[q*4+3]);
        *(us4*)(sp0 + q * 256) = o0;
        *(us4*)(sp1 + q * 256) = o1;
    }

    if (l == 0) {
        float* mlp = mlpart + (((long)b * 8 + w) * 2) * 2;
        mlp[0] = m0; mlp[1] = l0; mlp[2] = m1; mlp[3] = l1;
    }
}

// ---------------------------------------------------------------------------
// Combine 8 per-wave partials -> normalized sums (proven).
// ---------------------------------------------------------------------------
__global__ __launch_bounds__(256)
void attn_combine8(const unsigned short* __restrict__ spart_bf,
                   const float* __restrict__ mlpart,
                   unsigned short* __restrict__ sac_bf)
{
    const int b = blockIdx.x;
    const int tid = threadIdx.x;
    const int h = tid >> 7, d0 = (tid & 127) * 8;

    float m[8], lv[8];
#pragma unroll
    for (int c = 0; c < 8; ++c) {
        const float* mlp = mlpart + (((long)b * 8 + c) * 2 + h) * 2;
        m[c] = mlp[0]; lv[c] = mlp[1];
    }
    float ms = m[0];
#pragma unroll
    for (int c = 1; c < 8; ++c) ms = fmaxf(ms, m[c]);
    float wgt[8], L = 0.f;
#pragma unroll
    for (int c = 0; c < 8; ++c) { wgt[c] = __expf(m[c] - ms); L += wgt[c] * lv[c]; }
    const float inv = 1.0f / L;

    float acc[8] = {};
#pragma unroll
    for (int c = 0; c < 8; ++c) {
        us8 sv = *(const us8*)(spart_bf + (((long)b * 8 + c) * 2 + h) * 1024 + d0);
#pragma unroll
        for (int j = 0; j < 8; ++j)
            acc[j] += wgt[c] * bf2f(sv[j]);
    }
    us8 o;
#pragma unroll
    for (int j = 0; j < 8; ++j) o[j] = f2bf(acc[j] * inv);
    *(us8*)(sac_bf + (long)b * 2048 + h * kD + d0) = o;
}

// ---------------------------------------------------------------------------
// Fused LSTM cell + LayerNorm, reading TWO gate partials + both biases.
// ---------------------------------------------------------------------------
__device__ __forceinline__ float sigm(float x) { return 1.0f / (1.0f + __expf(-x)); }

__global__ __launch_bounds__(256)
void lstm_ln2(const float* __restrict__ gA, const float* __restrict__ gB,
              const float* __restrict__ b_ih, const float* __restrict__ b_hh,
              const float* __restrict__ cin,
              const float* __restrict__ ln_w, const float* __restrict__ ln_b,
              float* __restrict__ out0, float* __restrict__ out1)
{
    __shared__ float red[2][4];
    __shared__ float stats[2];

    const int b = blockIdx.x;
    const int tid = threadIdx.x;
    const int d4 = tid * 4;
    const float* ga = gA + (long)b * 4096;
    const float* gb = gB + (long)b * 4096;

    float iv[4], fv[4], gv[4], ov[4];
#pragma unroll
    for (int gidx = 0; gidx < 4; ++gidx) {
        const int off = gidx * 1024 + d4;
        float4 a = *(const float4*)(ga + off);
        float4 bq = *(const float4*)(gb + off);
        float4 bi = *(const float4*)(b_ih + off);
        float4 bh = *(const float4*)(b_hh + off);
        float* dstv = (gidx == 0) ? iv : (gidx == 1) ? fv : (gidx == 2) ? gv : ov;
        dstv[0] = a.x + bq.x + bi.x + bh.x;
        dstv[1] = a.y + bq.y + bi.y + bh.y;
        dstv[2] = a.z + bq.z + bi.z + bh.z;
        dstv[3] = a.w + bq.w + bi.w + bh.w;
    }
    float4 cv = *(const float4*)(cin + (long)b * kD + d4);
    float cc[4] = {cv.x, cv.y, cv.z, cv.w};

    float nc[4], nh[4];
#pragma unroll
    for (int u = 0; u < 4; ++u) {
        nc[u] = sigm(fv[u]) * cc[u] + sigm(iv[u]) * tanhf(gv[u]);
        nh[u] = sigm(ov[u]) * tanhf(nc[u]);
    }
    *(float4*)(out1 + (long)b * kD + d4) = make_float4(nc[0], nc[1], nc[2], nc[3]);

    float sum = nh[0] + nh[1] + nh[2] + nh[3];
    float ss  = nh[0]*nh[0] + nh[1]*nh[1] + nh[2]*nh[2] + nh[3]*nh[3];
#pragma unroll
    for (int m = 32; m >= 1; m >>= 1) {
        sum += __shfl_xor(sum, m);
        ss  += __shfl_xor(ss, m);
    }
    const int wave = tid >> 6, lane = tid & 63;
    if (lane == 0) { red[0][wave] = sum; red[1][wave] = ss; }
    __syncthreads();
    if (tid == 0) {
        float s = red[0][0] + red[0][1] + red[0][2] + red[0][3];
        float q = red[1][0] + red[1][1] + red[1][2] + red[1][3];
        float mu = s / (float)kD;
        float var = q / (float)kD - mu * mu;
        stats[0] = mu;
        stats[1] = rsqrtf(var + 1e-5f);
    }
    __syncthreads();
    const float mu = stats[0], rstd = stats[1];
    float4 lw = *(const float4*)(ln_w + d4);
    float4 lb = *(const float4*)(ln_b + d4);
    float lwv[4] = {lw.x, lw.y, lw.z, lw.w};
    float lbv[4] = {lb.x, lb.y, lb.z, lb.w};
    float o[4];
#pragma unroll
    for (int u = 0; u < 4; ++u)
        o[u] = (nh[u] - mu) * rstd * lwv[u] + lbv[u];
    *(float4*)(out0 + (long)b * kD + d4) = make_float4(o[0], o[1], o[2], o[3]);
}

// ---------------------------------------------------------------------------
extern "C" void kernel_launch(void* const* d_in, const int* in_sizes, int n_in,
                              void* d_out, int out_size, void* d_ws, size_t ws_size,
                              hipStream_t stream)
{
    (void)in_sizes; (void)n_in; (void)out_size;

    const float* h    = (const float*)d_in[0];
    const float* c    = (const float*)d_in[1];
    const float* xall = (const float*)d_in[2];
    const float* ext  = (const float*)d_in[3];
    const float* in_w = (const float*)d_in[4];
    const float* in_b = (const float*)d_in[5];
    const float* wo   = (const float*)d_in[6];
    const float* bo   = (const float*)d_in[7];
    const float* w_ih = (const float*)d_in[8];
    const float* b_ih = (const float*)d_in[9];
    const float* w_hh = (const float*)d_in[10];
    const float* b_hh = (const float*)d_in[11];
    const float* ln_w = (const float*)d_in[12];
    const float* ln_b = (const float*)d_in[13];

    float* out0 = (float*)d_out;              // LN(new_h) [512x1024]
    float* out1 = out0 + (long)kB * kD;       // new_c     [512x1024]

    // ---- workspace layout (identical offsets to round 8/12/13)
    char* p = (char*)d_ws;
    const size_t need = 63062016ull;
    if (ws_size < need) return;

    p += 16384;                                                  // (spare)
    unsigned short* h_bf   = (unsigned short*)p; p += 1048576;   // [512][1024]
    unsigned short* wq_bf  = (unsigned short*)p; p += 2097152;   // [1024][1024]
    unsigned short* wkT_bf = (unsigned short*)p; p += 2097152;   // [2][1024][512]
    unsigned short* wv_bf  = (unsigned short*)p; p += 2097152;   // [1024][1024]
    unsigned short* wo_bf  = (unsigned short*)p; p += 2097152;   // [1024][1024]
    unsigned short* q_bf   = (unsigned short*)p; p += 1048576;   // [512][1024]
    unsigned short* sac_bf = (unsigned short*)p; p += 2097152;   // [512][2048]
    unsigned short* ctx_bf = (unsigned short*)p; p += 1048576;   // [512][1024]
    unsigned short* acat   = (unsigned short*)p; p += 3145728;   // [512][3072]
    unsigned short* wcat   = (unsigned short*)p; p += 25165824;  // [4096][3072]
    // overlay region: {qtl, spart, mlpart} (attention) / {gatesA,B} (later)
    char* ov = p;
    float*          qtl      = (float*)ov;                       // [512][2][1024] f32
    unsigned short* spart_bf = (unsigned short*)(ov + 4194304);  // [512][8][2][1024] bf16
    float*          mlpart   = (float*)(ov + 4194304 + 16777216);// [512][8][2][2]
    float*          gatesA   = (float*)ov;                       // [512][4096] f32
    float*          gatesB   = (float*)(ov + 8388608);           // [512][4096] f32

    const float* wk_f = in_w + (long)kD * kD;
    const float* bq = in_b;
    const float* bv = in_b + 2 * kD;

    auto cvt = [&](const float* src, unsigned short* dst, int rows, int scols,
                   int dcols, int coloff) {
        int n8 = rows * (scols / 8);
        cvt_bf16<<<(n8 + 255) / 256, 256, 0, stream>>>(src, dst, scols / 8, dcols, coloff, n8);
    };

    // ---- conversions (proven 7-launch form)
    cvt(h, h_bf, 512, 1024, 1024, 0);
    cvt(in_w, wq_bf, 1024, 1024, 1024, 0);
    tcvt_wk<<<dim3(32, 16, 2), 256, 0, stream>>>(wk_f, wkT_bf);
    cvt(in_w + 2L * kD * kD, wv_bf, 1024, 1024, 1024, 0);
    cvt(wo, wo_bf, 1024, 1024, 1024, 0);
    cvt(w_ih, wcat, 4096, 2048, 3072, 0);
    cvt(w_hh, wcat, 4096, 1024, 3072, 2048);

    // 1. q_bf = bf16(h @ wq^T + bq)   (BK=64: 16 K-iterations)
    gemm32<<<dim3(16, 16, 1), 256, 0, stream>>>(
        h_bf, 1024, 0, wq_bf, 1024, 0,
        nullptr, 0, 0, q_bf, 1024, 0, bq, 0, 1024);

    // 2. qtl[:, z, :] = q_z @ wkT_z^T   (BK=64: 8 K-iterations)
    gemm32<<<dim3(16, 16, 2), 256, 0, stream>>>(
        q_bf, 1024, 512, wkT_bf, 512, 524288,
        qtl, 2048, 1024, nullptr, 0, 0, nullptr, 0, 512);

    // 3. streaming attention -> partials (frozen; ~88% of achievable BW)
    attn7<<<kB, 512, 0, stream>>>(xall, qtl, spart_bf, mlpart);

    // 4. combine 8 partials -> sac_bf (bf16)
    attn_combine8<<<kB, 256, 0, stream>>>(spart_bf, mlpart, sac_bf);

    // 5. ctx_bf[:, z*512:] = bf16(s_z @ wv_z^T + bv_z)
    gemm32<<<dim3(8, 16, 2), 256, 0, stream>>>(
        sac_bf, 2048, 1024, wv_bf, 1024, 524288,
        nullptr, 0, 0, ctx_bf, 1024, 512, bv, 512, 1024);

    // 6. acat[:, 0:1024] = bf16(ctx @ wo^T + bo)
    gemm32<<<dim3(16, 16, 1), 256, 0, stream>>>(
        ctx_bf, 1024, 0, wo_bf, 1024, 0,
        nullptr, 0, 0, acat, 3072, 0, bo, 0, 1024);

    // remaining acat columns
    cvt(ext, acat, 512, 1024, 3072, 1024);
    cvt(h,   acat, 512, 1024, 3072, 2048);

    // 7. gates partials = acat @ wcat^T, K split 2x (1024 blocks = 4/CU)
    gemm_gates_sk<<<dim3(64, 8, 2), 256, 0, stream>>>(
        acat, 3072, wcat, 3072, gatesA, 4096, 2097152);

    // 8. LSTM cell (gatesA+gatesB+b_ih+b_hh) + LayerNorm
    lstm_ln2<<<kB, 256, 0, stream>>>(gatesA, gatesB, b_ih, b_hh,
                                     c, ln_w, ln_b, out0, out1);
}